// Round 11
// baseline (611.276 us; speedup 1.0000x reference)
//
#include <hip/hip_runtime.h>
#include <hip/hip_fp16.h>
#include <math.h>

#define NN   50000
#define TT   16
#define EE   800000
#define BB   2000
#define EMBD 32
#define ENC  64
#define DEC  128
#define OUTL 25
#define BN_EPS 1e-5f

typedef short v8s __attribute__((ext_vector_type(8)));
typedef float v4f __attribute__((ext_vector_type(4)));
#define MFMA16(a,b,c) __builtin_amdgcn_mfma_f32_16x16x32_bf16((a),(b),(c),0,0,0)

__device__ __forceinline__ float lrelu(float v){ return v >= 0.f ? v : 0.1f*v; }
__device__ __forceinline__ float fsig(float v){ return __builtin_amdgcn_rcpf(1.f + __expf(-v)); }
__device__ __forceinline__ float ftanh(float v){ return 2.f*__builtin_amdgcn_rcpf(1.f + __expf(-2.f*v)) - 1.f; }
__device__ __forceinline__ float fsoftplus(float v){
    return v > 15.f ? v : __logf(1.f + __expf(v));
}

__device__ __forceinline__ unsigned short f2bf(float f){
    unsigned u = __float_as_uint(f);
    u = u + 0x7FFFu + ((u>>16)&1u);
    return (unsigned short)(u>>16);
}
__device__ __forceinline__ float bf2f(unsigned short s){ return __uint_as_float(((unsigned)s)<<16); }

// truncation-based hi/lo split (R12)
__device__ __forceinline__ void tsplit(float v, unsigned short& hi, unsigned short& lo){
    unsigned u = __float_as_uint(v);
    hi = (unsigned short)(u >> 16);
    float r = v - __uint_as_float(u & 0xFFFF0000u);
    lo = (unsigned short)(__float_as_uint(r) >> 16);
}

__device__ __forceinline__ v8s as_v8s(int4 v){
    union { int4 i; v8s s; } u; u.i = v; return u.s;
}

__device__ __forceinline__ void cvt8(const float* p, v8s& hi, v8s& lo){
    float4 a0 = *(const float4*)p;
    float4 a1 = *(const float4*)(p+4);
    float av[8] = {a0.x,a0.y,a0.z,a0.w,a1.x,a1.y,a1.z,a1.w};
#pragma unroll
    for (int j=0;j<8;j++){
        unsigned short h = f2bf(av[j]);
        hi[j] = (short)h;
        lo[j] = (short)f2bf(av[j] - bf2f(h));
    }
}
// reconstruct hi+lo, lrelu, re-split
__device__ __forceinline__ void lrelu_resplit(v8s hh, v8s hl, v8s& oh, v8s& ol){
#pragma unroll
    for (int j=0;j<8;j++){
        float v = bf2f((unsigned short)hh[j]) + bf2f((unsigned short)hl[j]);
        float a = lrelu(v);
        unsigned short h = f2bf(a);
        oh[j] = (short)h;
        ol[j] = (short)f2bf(a - bf2f(h));
    }
}

// ---------------- fused packing helpers ----------------
__device__ __forceinline__ void pf_item(const float* W, int K, int KB, int i,
                                        unsigned short* out){
    int l = i & 63, fb = i >> 6;
    int kb = fb % KB, nt = fb / KB;
    int n = nt*16 + (l&15);
    int k0 = kb*32 + ((l>>4)*8);
#pragma unroll
    for (int j=0;j<8;j++) out[i*8+j] = f2bf(W[(size_t)n*K + k0 + j]);
}
__device__ __forceinline__ void phl_item(const float* W, int K, int KB, int i,
                                         unsigned short* hi, unsigned short* lo){
    int l = i & 63, fb = i >> 6;
    int kb = fb % KB, nt = fb / KB;
    int n = nt*16 + (l&15);
    int k0 = kb*32 + ((l>>4)*8);
#pragma unroll
    for (int j=0;j<8;j++){
        float v = W[(size_t)n*K + k0 + j];
        unsigned short h = f2bf(v);
        hi[i*8+j] = h;
        lo[i*8+j] = f2bf(v - bf2f(h));
    }
}
__device__ __forceinline__ void pcat_item(const float* Wa, const float* Wb,
                                          int K1, int K, int KB, int i,
                                          unsigned short* out){
    int l = i & 63, fb = i >> 6;
    int kb = fb % KB, nt = fb / KB;
    int n = nt*16 + (l&15);
    int k0 = kb*32 + ((l>>4)*8);
#pragma unroll
    for (int j=0;j<8;j++){
        int k = k0 + j;
        float v = (k < K1) ? Wa[(size_t)n*K1 + k] : Wb[(size_t)n*(K-K1) + (k-K1)];
        out[i*8+j] = f2bf(v);
    }
}
__device__ __forceinline__ void pproj_item(const float* Wf, const float* Ws, int i,
                                           unsigned short* hi, unsigned short* lo){
    int l = i & 63, fb = i >> 6;
    int kb = fb & 1, nt = fb >> 1;
    int n = nt*16 + (l&15);
    int d = n >> 6, c = n & 63;
    const float* W = (d < 2) ? Wf : Ws;
    int k0 = (d&1)*64 + kb*32 + ((l>>4)*8);
#pragma unroll
    for (int j=0;j<8;j++){
        float v = W[c*130 + k0 + j];
        unsigned short h = f2bf(v);
        hi[i*8+j] = h;
        lo[i*8+j] = f2bf(v - bf2f(h));
    }
}

// ---------------- all weight prep in ONE dispatch ----------------
__global__ void pack_all(
    const float* __restrict__ gWih, const float* __restrict__ gWhh,
    const float* __restrict__ Wdyn,
    const float* __restrict__ l0Whh, const float* __restrict__ l1Wih,
    const float* __restrict__ l1Whh, const float* __restrict__ l0Wih,
    const float* __restrict__ c1Wf, const float* __restrict__ c1Ws,
    const float* __restrict__ c2Wf, const float* __restrict__ c2Ws,
    unsigned short* __restrict__ pWih, unsigned short* __restrict__ pWhh,
    unsigned short* __restrict__ pWdyn,
    unsigned short* __restrict__ B0h, unsigned short* __restrict__ B1h,
    unsigned short* __restrict__ P1h, unsigned short* __restrict__ P1l,
    unsigned short* __restrict__ P2h, unsigned short* __restrict__ P2l,
    unsigned short* __restrict__ GIh, unsigned short* __restrict__ GIl,
    int* __restrict__ cnt, int* __restrict__ gtot)
{
    int i = blockIdx.x*256 + threadIdx.x;
    if (i < 768){ pf_item(gWih, 32, 1, i, pWih); return; }   i -= 768;
    if (i < 1536){ pf_item(gWhh, 64, 2, i, pWhh); return; }  i -= 1536;
    if (i < 512){ pf_item(Wdyn, 64, 2, i, pWdyn); return; }  i -= 512;
    if (i < 8192){ pcat_item(l0Whh, l0Whh, 128, 128, 4, i, B0h); return; } i -= 8192;
    if (i < 16384){ pcat_item(l1Wih, l1Whh, 128, 256, 8, i, B1h); return; } i -= 16384;
    if (i < 2048){ pproj_item(c1Wf, c1Ws, i, P1h, P1l); return; } i -= 2048;
    if (i < 2048){ pproj_item(c2Wf, c2Ws, i, P2h, P2l); return; } i -= 2048;
    if (i < 8192){ phl_item(l0Wih, 128, 4, i, GIh, GIl); return; } i -= 8192;
    if (i < NN){ cnt[i] = 0; return; } i -= NN;
    if (i < 1){ gtot[0] = 0; return; }
}
#define PACK_TOTAL (768+1536+512+8192+16384+2048+2048+8192+NN+1)

// ---------------- GRU encoder v12 (R9 best; unchanged) ----------------
__global__ __launch_bounds__(256) void encoder_mfma(
    const float* __restrict__ x,
    const float* __restrict__ Wip, const float* __restrict__ bip,
    const unsigned short* __restrict__ pWih,
    const unsigned short* __restrict__ pWhh,
    const float* __restrict__ bih, const float* __restrict__ bhh,
    const unsigned short* __restrict__ pWdyn,
    const float* __restrict__ bdyn,
    float* __restrict__ hist)
{
    __shared__ unsigned short efh[4*512], efl[4*512];          // e A-frags, 4-step window
    __shared__ unsigned short hfh[2][1024], hfl[2][1024];      // dbuf h A-frags (swizzled)
    const int tid = threadIdx.x;
    const int l   = tid & 63;
    const int w   = tid >> 6;          // wave owns g-tile w
    const int ln  = l & 15, q = l >> 4;
    const int blk = blockIdx.x;
    const int rsw = ((l>>1)&7)<<3;     // read swizzle key

    for (int i = tid; i < 1024; i += 256){
        hfh[0][i]=0; hfl[0][i]=0; hfh[1][i]=0; hfl[1][i]=0;
    }

    // e-compute decomposition: thread owns ONE k (3 weight regs) + 2 nodes
    const int k0 = tid & 31;
    const int mb = tid >> 5;           // nodes 2mb, 2mb+1
    const float ew0 = Wip[2*k0], ew1 = Wip[2*k0+1], ebk = bip[k0];
    const int ebase = (k0>>3)*128 + (k0&7);
    const float2* xr0 = (const float2*)(x + (size_t)(blk*16 + 2*mb    )*32);
    const float2* xr1 = (const float2*)(x + (size_t)(blk*16 + 2*mb + 1)*32);

    const int c = w*16 + ln;
    const float bR  = bih[c]       + bhh[c];
    const float bZ  = bih[64 + c]  + bhh[64 + c];
    const float bNI = bih[128 + c];
    const float bNH = bhh[128 + c];
    float hprev[4] = {0.f,0.f,0.f,0.f};

    const v8s* FIH = (const v8s*)pWih;
    const v8s* FHH = (const v8s*)pWhh;
    const v8s* FDY = (const v8s*)pWdyn;
    const int wbase = (c>>5)*512 + (16*((c&31)>>3))*8 + (c&7);
    __syncthreads();                   // h zero-init ready

    int p = 0;
#pragma unroll 1
    for (int tb = 0; tb < 4; tb++){
#pragma unroll
        for (int ts = 0; ts < 4; ts++){
            int t = tb*4 + ts;
            float2 xv0 = xr0[t], xv1 = xr1[t];
            float e0 = lrelu(ew0*xv0.x + ew1*xv0.y + ebk);
            float e1 = lrelu(ew0*xv1.x + ew1*xv1.y + ebk);
            unsigned short h_, l_;
            tsplit(e0, h_, l_);
            efh[ts*512 + ebase + (2*mb  )*8] = h_;
            efl[ts*512 + ebase + (2*mb  )*8] = l_;
            tsplit(e1, h_, l_);
            efh[ts*512 + ebase + (2*mb+1)*8] = h_;
            efl[ts*512 + ebase + (2*mb+1)*8] = l_;
        }
        __syncthreads();               // ef window ready
#pragma unroll 1
        for (int ts = 0; ts < 4; ts++){
            v8s eh  = *(const v8s*)&efh[ts*512 + l*8];
            v8s el  = *(const v8s*)&efl[ts*512 + l*8];
            v8s h0h = *(const v8s*)&hfh[p][(l*8) ^ rsw];
            v8s h0l = *(const v8s*)&hfl[p][(l*8) ^ rsw];
            v8s h1h = *(const v8s*)&hfh[p][512 + ((l*8) ^ rsw)];
            v8s h1l = *(const v8s*)&hfl[p][512 + ((l*8) ^ rsw)];

            v4f aR = {bR,bR,bR,bR};
            v4f aZ = {bZ,bZ,bZ,bZ};
            v4f aNI= {bNI,bNI,bNI,bNI};
            v4f aNH= {bNH,bNH,bNH,bNH};
            v8s b;
            b = FIH[(w   )*64 + l];    aR = MFMA16(eh,b,aR);  aR = MFMA16(el,b,aR);
            b = FHH[(w*2+0)*64+l];     aR = MFMA16(h0h,b,aR); aR = MFMA16(h0l,b,aR);
            b = FHH[(w*2+1)*64+l];     aR = MFMA16(h1h,b,aR); aR = MFMA16(h1l,b,aR);
            b = FIH[(4+w )*64 + l];    aZ = MFMA16(eh,b,aZ);  aZ = MFMA16(el,b,aZ);
            b = FHH[((4+w)*2+0)*64+l]; aZ = MFMA16(h0h,b,aZ); aZ = MFMA16(h0l,b,aZ);
            b = FHH[((4+w)*2+1)*64+l]; aZ = MFMA16(h1h,b,aZ); aZ = MFMA16(h1l,b,aZ);
            b = FIH[(8+w )*64 + l];    aNI= MFMA16(eh,b,aNI); aNI= MFMA16(el,b,aNI);
            b = FHH[((8+w)*2+0)*64+l]; aNH= MFMA16(h0h,b,aNH);aNH= MFMA16(h0l,b,aNH);
            b = FHH[((8+w)*2+1)*64+l]; aNH= MFMA16(h1h,b,aNH);aNH= MFMA16(h1l,b,aNH);

#pragma unroll
            for (int i = 0; i < 4; i++){
                float r_ = fsig(aR[i]);
                float z_ = fsig(aZ[i]);
                float nn_ = ftanh(aNI[i] + r_*aNH[i]);
                float hn = nn_ + z_*(hprev[i] - nn_);
                hprev[i] = hn;
                int row = q*4 + i;
                int off = (wbase + row*8) ^ ((((row)>>1)&7)<<3);
                unsigned short hh_, hl_;
                tsplit(hn, hh_, hl_);
                hfh[1-p][off] = hh_;
                hfl[1-p][off] = hl_;
            }
            __syncthreads();   // per-step barrier
            p ^= 1;
        }
    }
    {
        v8s a0h,a0l,a1h,a1l;
        lrelu_resplit(*(const v8s*)&hfh[p][(l*8) ^ rsw],
                      *(const v8s*)&hfl[p][(l*8) ^ rsw],       a0h, a0l);
        lrelu_resplit(*(const v8s*)&hfh[p][512 + ((l*8) ^ rsw)],
                      *(const v8s*)&hfl[p][512 + ((l*8) ^ rsw)], a1h, a1l);
        const int nt = w;
        float bb = bdyn[nt*16 + ln];
        v4f acc = {bb,bb,bb,bb};
        v8s b;
        b = FDY[(nt*2+0)*64 + l]; acc = MFMA16(a0h,b,acc); acc = MFMA16(a0l,b,acc);
        b = FDY[(nt*2+1)*64 + l]; acc = MFMA16(a1h,b,acc); acc = MFMA16(a1l,b,acc);
#pragma unroll
        for (int i = 0; i < 4; i++){
            hist[(size_t)(blk*16 + q*4 + i)*64 + nt*16 + ln] = lrelu(acc[i]);
        }
    }
}

// ---------------- CGConv projections v2: f16-packed B-gates (unchanged) ----------------
#define PROJ_ACC(NT, ACC) { \
    v8s bh0_ = FH[((NT)*2+0)*64 + l], bl0_ = FL[((NT)*2+0)*64 + l]; \
    v8s bh1_ = FH[((NT)*2+1)*64 + l], bl1_ = FL[((NT)*2+1)*64 + l]; \
    ACC = MFMA16(ah0,bh0_,ACC); ACC = MFMA16(al0,bh0_,ACC); ACC = MFMA16(ah0,bl0_,ACC); \
    ACC = MFMA16(ah1,bh1_,ACC); ACC = MFMA16(al1,bh1_,ACC); ACC = MFMA16(ah1,bl1_,ACC); }

__global__ __launch_bounds__(256) void proj_mfma(
    const float* __restrict__ xin,
    const unsigned short* __restrict__ Bh, const unsigned short* __restrict__ Bl,
    float* __restrict__ Af, float* __restrict__ As,
    unsigned* __restrict__ BP)
{
    __shared__ float sx[64*68];
    const int tid = threadIdx.x;
    const int l = tid & 63;
    const int w = tid >> 6;
    const int ln = l & 15, q = l >> 4;
    const int n0 = blockIdx.x*64;

    for (int i=tid;i<64*16;i+=256){
        int nn = i>>4, f4 = i&15;
        float4 v = {0.f,0.f,0.f,0.f};
        if (n0+nn < NN) v = ((const float4*)(xin + (size_t)(n0+nn)*64))[f4];
        *(float4*)&sx[nn*68 + f4*4] = v;
    }
    __syncthreads();

    v8s ah0,al0,ah1,al1;
    cvt8(&sx[(w*16+ln)*68 +      q*8], ah0, al0);
    cvt8(&sx[(w*16+ln)*68 + 32 + q*8], ah1, al1);

    const v8s* FH = (const v8s*)Bh;
    const v8s* FL = (const v8s*)Bl;
#pragma unroll 1
    for (int c3=0; c3<4; c3++){
        v4f aA = {0.f,0.f,0.f,0.f};
        v4f aS = aA, aF = aA, aB = aA;
        PROJ_ACC(c3,      aA);
        PROJ_ACC(8 + c3,  aS);
        PROJ_ACC(4 + c3,  aF);
        PROJ_ACC(12 + c3, aB);
        int col = c3*16 + ln;
#pragma unroll
        for (int i=0;i<4;i++){
            int node = n0 + w*16 + q*4 + i;
            if (node < NN){
                Af[(size_t)node*64 + col] = aA[i];
                As[(size_t)node*64 + col] = aS[i];
                unsigned pf = __half_as_ushort(__float2half(aF[i]));
                unsigned ps = __half_as_ushort(__float2half(aB[i]));
                BP[(size_t)node*64 + col] = pf | (ps << 16);
            }
        }
    }
}

// ---------------- dst segment build: histogram + atomic alloc + scatter ----------------
__global__ void count_kernel(const int* __restrict__ ei, int* __restrict__ cnt){
    int e = blockIdx.x*256 + threadIdx.x;
    if (e < EE) atomicAdd(&cnt[ei[EE+e]], 1);
}

__global__ void alloc_kernel(const int* __restrict__ cnt, int* __restrict__ gtot,
                             int* __restrict__ off, int* __restrict__ cur){
    int n = blockIdx.x*256 + threadIdx.x;
    if (n >= NN) return;
    int c = cnt[n];
    int s = atomicAdd(gtot, c);
    off[n] = s;
    cur[n] = s;
}

// scatter: 8-byte records {src:int, ea:2xf16} (R23: halves record traffic
// in scatter writes + both cg_agg reads; ea f16 err ~1e-4 through the gates)
__global__ void scatter_kernel(const int* __restrict__ ei, const float* __restrict__ ea,
                               int* __restrict__ cur, int2* __restrict__ recS){
    int e = blockIdx.x*256 + threadIdx.x;
    if (e >= EE) return;
    int d = ei[EE+e];
    int p = atomicAdd(&cur[d], 1);
    unsigned e0 = __half_as_ushort(__float2half(ea[2*(size_t)e]));
    unsigned e1 = __half_as_ushort(__float2half(ea[2*(size_t)e+1]));
    int2 r;
    r.x = ei[e];
    r.y = (int)(e0 | (e1 << 16));
    recS[p] = r;
}

// ---------------- CGConv aggregate: 8B records + f16 B-gate gather ----------------
__global__ __launch_bounds__(256) void cg_agg(
    const float* __restrict__ xin,
    const int2* __restrict__ recS,
    const int* __restrict__ off, const int* __restrict__ cnt,
    const float* __restrict__ Wf, const float* __restrict__ bf,
    const float* __restrict__ Ws, const float* __restrict__ bs,
    const float* __restrict__ Af, const float* __restrict__ As,
    const unsigned* __restrict__ BP,
    const float* __restrict__ gamma, const float* __restrict__ beta,
    const float* __restrict__ mean, const float* __restrict__ var,
    float* __restrict__ outp)
{
    const int tid = threadIdx.x;
    const int c = tid & 63, wid = tid >> 6;
    const int n = blockIdx.x*4 + wid;
    if (n >= NN) return;

    const float wf0 = Wf[c*130+128], wf1 = Wf[c*130+129], bfc = bf[c];
    const float ws0 = Ws[c*130+128], ws1 = Ws[c*130+129], bsc = bs[c];
    const float afd = Af[(size_t)n*64+c] + bfc, asd = As[(size_t)n*64+c] + bsc;
    const unsigned* BPc = BP + c;

    float acc = 0.f;
    int i = off[n];
    const int i1 = i + cnt[n];
#pragma unroll 1
    for (; i+1 < i1; i += 2){
        int2 r0 = recS[i], r1 = recS[i+1];
        unsigned ea0 = (unsigned)r0.y, ea1 = (unsigned)r1.y;
        float e00 = __half2float(__ushort_as_half((unsigned short)(ea0 & 0xFFFFu)));
        float e01 = __half2float(__ushort_as_half((unsigned short)(ea0 >> 16)));
        float e10 = __half2float(__ushort_as_half((unsigned short)(ea1 & 0xFFFFu)));
        float e11 = __half2float(__ushort_as_half((unsigned short)(ea1 >> 16)));
        unsigned pv0 = BPc[(size_t)r0.x*64];
        unsigned pv1 = BPc[(size_t)r1.x*64];
        float bf0v = __half2float(__ushort_as_half((unsigned short)(pv0 & 0xFFFFu)));
        float bs0v = __half2float(__ushort_as_half((unsigned short)(pv0 >> 16)));
        float bf1v = __half2float(__ushort_as_half((unsigned short)(pv1 & 0xFFFFu)));
        float bs1v = __half2float(__ushort_as_half((unsigned short)(pv1 >> 16)));
        float gf0 = afd + bf0v + wf0*e00 + wf1*e01;
        float gs0 = asd + bs0v + ws0*e00 + ws1*e01;
        float gf1 = afd + bf1v + wf0*e10 + wf1*e11;
        float gs1 = asd + bs1v + ws0*e10 + ws1*e11;
        acc += fsig(gf0)*fsoftplus(gs0);
        acc += fsig(gf1)*fsoftplus(gs1);
    }
    if (i < i1){
        int2 r0 = recS[i];
        unsigned ea0 = (unsigned)r0.y;
        float e00 = __half2float(__ushort_as_half((unsigned short)(ea0 & 0xFFFFu)));
        float e01 = __half2float(__ushort_as_half((unsigned short)(ea0 >> 16)));
        unsigned pv0 = BPc[(size_t)r0.x*64];
        float bf0v = __half2float(__ushort_as_half((unsigned short)(pv0 & 0xFFFFu)));
        float bs0v = __half2float(__ushort_as_half((unsigned short)(pv0 >> 16)));
        float gf = afd + bf0v + wf0*e00 + wf1*e01;
        float gs = asd + bs0v + ws0*e00 + ws1*e01;
        acc += fsig(gf)*fsoftplus(gs);
    }
    float bn = (acc - mean[c])*rsqrtf(var[c]+BN_EPS)*gamma[c] + beta[c];
    outp[(size_t)n*64+c] = xin[(size_t)n*64+c] + bn;
}

// ---------------- target gather + nbrs linear + concat (unchanged) ----------------
__global__ __launch_bounds__(256) void target_kernel(
    const float* __restrict__ hist, const float* __restrict__ f2,
    const int* __restrict__ tgt,
    const float* __restrict__ Wn, const float* __restrict__ bn_,
    float* __restrict__ enc)
{
    const int tid=threadIdx.x;
    const int c = tid&63, q = tid>>6;
    const int b = blockIdx.x*4 + q;
    if (b>=BB) return;
    const int n = tgt[b];
    float a = bn_[c];
#pragma unroll
    for (int k=0;k<ENC;k++) a += Wn[c*64+k]*f2[(size_t)n*64+k];
    enc[(size_t)b*128 + 64 + c] = lrelu(a);
    enc[(size_t)b*128 + c]      = hist[(size_t)n*64+c];
}

// ---------------- gi0 via MFMA (unchanged) ----------------
__global__ __launch_bounds__(512) void gi0_mfma(
    const float* __restrict__ enc,
    const unsigned short* __restrict__ GIh, const unsigned short* __restrict__ GIl,
    const float* __restrict__ bih0, const float* __restrict__ bhh0,
    float* __restrict__ gi0)
{
    __shared__ float senc[16*132];
    const int tid = threadIdx.x;
    const int l = tid & 63;
    const int w = tid >> 6;
    const int ln = l & 15, q = l >> 4;
    const int b0 = blockIdx.x*16;

    for (int i=tid;i<16*32;i+=512){
        int row = i>>5, f4 = i&31;
        *(float4*)&senc[row*132 + f4*4] = ((const float4*)(enc + (size_t)(b0+row)*128))[f4];
    }
    __syncthreads();

    v8s ah[4], al[4];
#pragma unroll
    for (int kb=0;kb<4;kb++) cvt8(&senc[ln*132 + kb*32 + q*8], ah[kb], al[kb]);

    const v8s* FH = (const v8s*)GIh;
    const v8s* FL = (const v8s*)GIl;
#pragma unroll
    for (int u=0;u<4;u++){
        int nt = w*4 + u;
        int col = nt*16 + ln;
        float bb = bih0[col] + bhh0[col];
        v4f acc = {bb,bb,bb,bb};
#pragma unroll
        for (int kb=0;kb<4;kb++){
            v8s bh = FH[(nt*4+kb)*64 + l];
            v8s bl = FL[(nt*4+kb)*64 + l];
            acc = MFMA16(ah[kb],bh,acc); acc = MFMA16(al[kb],bh,acc); acc = MFMA16(ah[kb],bl,acc);
        }
#pragma unroll
        for (int i=0;i<4;i++)
            gi0[(size_t)(b0 + q*4 + i)*512 + col] = acc[i];
    }
}

// ---------------- 2-layer LSTM decoder v10: W0 in registers, no sW0 LDS ----------------
// R23: per-step sW0 reads (16 ds_read_b128/wave) have loop-invariant indices
// ((g*8+w)*4+kb) — hoist into W0r[16] registers like W1r. Deletes the 128KB
// sW0 LDS array + its staging pass; LDS 160KB -> 32KB. Register budget:
// W0r(64)+W1r(128)+state ~250 of 256/wave at waves_per_eu(2,2) — tight;
// failure mode (spill) is loud: lstm re-enters top-5 with exploded FETCH.
#define LMB 16
__global__ __launch_bounds__(512)
__attribute__((amdgpu_waves_per_eu(2,2)))
void lstm_mfma(
    const float* __restrict__ gi0,
    const unsigned short* __restrict__ B0h,
    const unsigned short* __restrict__ B1h,
    const float* __restrict__ bih1, const float* __restrict__ bhh1,
    float* __restrict__ h1buf)
{
    __shared__ unsigned short h0hi[2][4*512], h0lo[2][4*512];    // 16384 B
    __shared__ unsigned short h1hi[2][4*512], h1lo[2][4*512];    // 16384 B
    const int tid = threadIdx.x;
    const int l = tid & 63;
    const int w = tid >> 6;
    const int c = l & 15;
    const int q = l >> 4;
    const int j = w*16 + c;
    const int b0 = blockIdx.x*LMB;
    const int lsw = ((l>>1)&7)<<3;     // read swizzle key (row = l)

    for (int i=tid;i<4*512;i+=512){
        h0hi[0][i]=0; h0lo[0][i]=0; h0hi[1][i]=0; h0lo[1][i]=0;
        h1hi[0][i]=0; h1lo[0][i]=0; h1hi[1][i]=0; h1lo[1][i]=0;
    }

    int4 W0r[16];
    {
        const int4* F0 = (const int4*)B0h;
#pragma unroll
        for (int g=0;g<4;g++)
#pragma unroll
            for (int kb=0;kb<4;kb++) W0r[g*4+kb] = F0[((g*8+w)*4 + kb)*64 + l];
#pragma unroll
        for (int i=0;i<16;i++)
            asm volatile("" : "+v"(W0r[i].x), "+v"(W0r[i].y), "+v"(W0r[i].z), "+v"(W0r[i].w));
    }

    int4 W1r[32];
    {
        const int4* F1 = (const int4*)B1h;
#pragma unroll
        for (int g=0;g<4;g++)
#pragma unroll
            for (int kb=0;kb<8;kb++) W1r[g*8+kb] = F1[((g*8+w)*8 + kb)*64 + l];
#pragma unroll
        for (int i=0;i<32;i++)
            asm volatile("" : "+v"(W1r[i].x), "+v"(W1r[i].y), "+v"(W1r[i].z), "+v"(W1r[i].w));
    }

    float rgi[4][4];
#pragma unroll
    for (int g=0;g<4;g++)
#pragma unroll
        for (int i=0;i<4;i++)
            rgi[g][i] = gi0[(size_t)(b0 + q*4 + i)*512 + g*128 + j];

    float b1[4];
#pragma unroll
    for (int g=0;g<4;g++) b1[g] = bih1[g*128+j] + bhh1[g*128+j];
    float c0[4] = {0,0,0,0}, c1[4] = {0,0,0,0};
    const int kbw = j>>5, qw = (j>>3)&3, jw = j&7;
    __syncthreads();

    int p = 0;
#pragma unroll 1
    for (int t=0;t<OUTL;t++){
        // ---- layer 0: read h0[p], write h0[1-p]; dual hi/lo accumulators ----
        v4f aH[4], aL[4];
#pragma unroll
        for (int g=0;g<4;g++){
            v4f t4 = {rgi[g][0], rgi[g][1], rgi[g][2], rgi[g][3]};
            aH[g] = t4;
            v4f z = {0.f,0.f,0.f,0.f};
            aL[g] = z;
        }
#pragma unroll
        for (int kb=0;kb<4;kb++){
            v8s ah = *(const v8s*)&h0hi[p][kb*512 + ((l*8) ^ lsw)];
            v8s al = *(const v8s*)&h0lo[p][kb*512 + ((l*8) ^ lsw)];
#pragma unroll
            for (int g=0;g<4;g++){
                v8s bfr = as_v8s(W0r[g*4 + kb]);
                aH[g] = MFMA16(ah, bfr, aH[g]);
                aL[g] = MFMA16(al, bfr, aL[g]);
            }
        }
#pragma unroll
        for (int i=0;i<4;i++){
            float gi_ = aH[0][i]+aL[0][i], gf_ = aH[1][i]+aL[1][i];
            float gg_ = aH[2][i]+aL[2][i], go_ = aH[3][i]+aL[3][i];
            c0[i] = fsig(gf_)*c0[i] + fsig(gi_)*ftanh(gg_);
            float hn = fsig(go_)*ftanh(c0[i]);
            int row = q*4 + i;
            int off = (kbw*512 + (qw*16 + row)*8 + jw) ^ (((row>>1)&7)<<3);
            unsigned short h = f2bf(hn);
            h0hi[1-p][off] = h;
            h0lo[1-p][off] = f2bf(hn - bf2f(h));
        }
        __syncthreads();   // B1: the ONLY barrier per step

        // ---- layer 1: read h0[1-p] + h1[p], write h1[1-p] ----
        v4f bH[4], bL[4];
#pragma unroll
        for (int g=0;g<4;g++){
            v4f t4={b1[g],b1[g],b1[g],b1[g]}; bH[g]=t4;
            v4f z={0.f,0.f,0.f,0.f}; bL[g]=z;
        }
#pragma unroll
        for (int kb=0;kb<8;kb++){
            const unsigned short* hb = (kb<4) ? h0hi[1-p] : h1hi[p];
            const unsigned short* lb = (kb<4) ? h0lo[1-p] : h1lo[p];
            int kk = kb & 3;
            v8s ah = *(const v8s*)&hb[kk*512 + ((l*8) ^ lsw)];
            v8s al = *(const v8s*)&lb[kk*512 + ((l*8) ^ lsw)];
#pragma unroll
            for (int g=0;g<4;g++){
                bH[g] = MFMA16(ah, as_v8s(W1r[g*8+kb]), bH[g]);
                bL[g] = MFMA16(al, as_v8s(W1r[g*8+kb]), bL[g]);
            }
        }
        float h1new[4];
#pragma unroll
        for (int i=0;i<4;i++){
            float gi_ = bH[0][i]+bL[0][i], gf_ = bH[1][i]+bL[1][i];
            float gg_ = bH[2][i]+bL[2][i], go_ = bH[3][i]+bL[3][i];
            c1[i] = fsig(gf_)*c1[i] + fsig(gi_)*ftanh(gg_);
            h1new[i] = fsig(go_)*ftanh(c1[i]);
            int row = q*4 + i;
            int off = (kbw*512 + (qw*16 + row)*8 + jw) ^ (((row>>1)&7)<<3);
            unsigned short h = f2bf(h1new[i]);
            h1hi[1-p][off] = h;
            h1lo[1-p][off] = f2bf(h1new[i] - bf2f(h));
        }

        // ---- out-proj deferred: stream h1 (f32) to global scratch ----
#pragma unroll
        for (int i=0;i<4;i++){
            h1buf[((size_t)(b0 + q*4 + i)*OUTL + t)*DEC + j] = h1new[i];
        }
        p ^= 1;
    }
}

// ---------------- out-projection: fut = h1buf @ Wop^T + bop (unchanged) ----------------
__global__ __launch_bounds__(256) void out_proj(
    const float* __restrict__ h1buf,
    const float* __restrict__ Wop, const float* __restrict__ bop,
    float* __restrict__ outp)
{
    int idx = blockIdx.x*256 + threadIdx.x;      // idx = b*OUTL + t
    if (idx >= BB*OUTL) return;
    const float4* hp = (const float4*)(h1buf + (size_t)idx*DEC);
    const float4* w0 = (const float4*)Wop;
    const float4* w1 = (const float4*)(Wop + DEC);
    float a0 = 0.f, a1 = 0.f;
#pragma unroll
    for (int k=0;k<32;k++){
        float4 h = hp[k], x0 = w0[k], x1 = w1[k];
        a0 += h.x*x0.x + h.y*x0.y + h.z*x0.z + h.w*x0.w;
        a1 += h.x*x1.x + h.y*x1.y + h.z*x1.z + h.w*x1.w;
    }
    outp[(size_t)idx*2    ] = a0 + bop[0];
    outp[(size_t)idx*2 + 1] = a1 + bop[1];
}

extern "C" void kernel_launch(void* const* d_in, const int* in_sizes, int n_in,
                              void* d_out, int out_size, void* d_ws, size_t ws_size,
                              hipStream_t stream)
{
    const float* x    = (const float*)d_in[0];
    const int*   ei   = (const int*)d_in[1];
    const float* ea   = (const float*)d_in[2];
    const int*   tgt  = (const int*)d_in[3];
    const float* Wip  = (const float*)d_in[4];
    const float* bip  = (const float*)d_in[5];
    const float* gWih = (const float*)d_in[6];
    const float* gWhh = (const float*)d_in[7];
    const float* gbih = (const float*)d_in[8];
    const float* gbhh = (const float*)d_in[9];
    const float* Wdyn = (const float*)d_in[10];
    const float* bdyn = (const float*)d_in[11];
    const float* c1Wf=(const float*)d_in[12]; const float* c1bf=(const float*)d_in[13];
    const float* c1Ws=(const float*)d_in[14]; const float* c1bs=(const float*)d_in[15];
    const float* c1g =(const float*)d_in[16]; const float* c1b =(const float*)d_in[17];
    const float* c1m =(const float*)d_in[18]; const float* c1v =(const float*)d_in[19];
    const float* c2Wf=(const float*)d_in[20]; const float* c2bf=(const float*)d_in[21];
    const float* c2Ws=(const float*)d_in[22]; const float* c2bs=(const float*)d_in[23];
    const float* c2g =(const float*)d_in[24]; const float* c2b =(const float*)d_in[25];
    const float* c2m =(const float*)d_in[26]; const float* c2v =(const float*)d_in[27];
    const float* Wn  =(const float*)d_in[28]; const float* bn_ =(const float*)d_in[29];
    const float* l0Wih=(const float*)d_in[30]; const float* l0Whh=(const float*)d_in[31];
    const float* l0bih=(const float*)d_in[32]; const float* l0bhh=(const float*)d_in[33];
    const float* l1Wih=(const float*)d_in[34]; const float* l1Whh=(const float*)d_in[35];
    const float* l1bih=(const float*)d_in[36]; const float* l1bhh=(const float*)d_in[37];
    const float* Wop =(const float*)d_in[38]; const float* bop=(const float*)d_in[39];

    float* ws = (float*)d_ws;
    size_t o = 0;
    float* hist = ws + o; o += (size_t)NN*ENC;
    float* f1   = ws + o; o += (size_t)NN*ENC;
    float* f2   = ws + o; o += (size_t)NN*ENC;
    float* Af   = ws + o; o += (size_t)NN*ENC;
    float* Bfs  = ws + o; o += (size_t)NN*ENC;   // BP slot (u32 packed B-gates)
    float* As   = ws + o; o += (size_t)NN*ENC;
    float* enc  = ws + o; o += (size_t)BB*2*ENC;
    float* gi0  = ws + o; o += (size_t)BB*4*DEC;
    unsigned short* pWih  = (unsigned short*)(ws + o); o += (size_t)12*64*8/2;
    unsigned short* pWhh  = (unsigned short*)(ws + o); o += (size_t)24*64*8/2;
    unsigned short* pWdyn = (unsigned short*)(ws + o); o += (size_t)8*64*8/2;
    unsigned short* B0h = (unsigned short*)(ws + o); o += (size_t)32*4*64*8/2;
    unsigned short* B1h = (unsigned short*)(ws + o); o += (size_t)32*8*64*8/2;
    unsigned short* P1h = (unsigned short*)(ws + o); o += (size_t)2048*8/2;
    unsigned short* P1l = (unsigned short*)(ws + o); o += (size_t)2048*8/2;
    unsigned short* P2h = (unsigned short*)(ws + o); o += (size_t)2048*8/2;
    unsigned short* P2l = (unsigned short*)(ws + o); o += (size_t)2048*8/2;
    unsigned short* GIh = (unsigned short*)(ws + o); o += (size_t)8192*8/2;
    unsigned short* GIl = (unsigned short*)(ws + o); o += (size_t)8192*8/2;
    int* cnt    = (int*)(ws + o); o += NN;
    int* offv   = (int*)(ws + o); o += NN+1;
    int* curv   = (int*)(ws + o); o += NN;
    int* gtot   = (int*)(ws + o); o += 1;
    o = (o + 3) & ~(size_t)3;               // align for int2 records
    int2* recS  = (int2*)(ws + o); o += (size_t)2*EE;

    unsigned* BP = (unsigned*)Bfs;

    // h1buf (BB*OUTL*DEC = 6.4M floats) aliases Af..Bfs (2*NN*ENC = 6.4M
    // floats): both dead after cg_agg #2 (stream-ordered before lstm_mfma).
    float* h1buf = Af;

    // --- all weight prep + cnt/gtot zero in one dispatch ---
    pack_all<<<(PACK_TOTAL+255)/256, 256, 0, stream>>>(
        gWih, gWhh, Wdyn, l0Whh, l1Wih, l1Whh, l0Wih,
        c1Wf, c1Ws, c2Wf, c2Ws,
        pWih, pWhh, pWdyn, B0h, B1h, P1h, P1l, P2h, P2l, GIh, GIl, cnt, gtot);

    // --- dst segment build (order-free atomic allocation) ---
    count_kernel<<<(EE+255)/256, 256, 0, stream>>>(ei, cnt);
    alloc_kernel<<<(NN+255)/256, 256, 0, stream>>>(cnt, gtot, offv, curv);
    scatter_kernel<<<(EE+255)/256, 256, 0, stream>>>(ei, ea, curv, recS);

    // --- history encoder (MFMA) ---
    encoder_mfma<<<NN/16, 256, 0, stream>>>(x, Wip, bip, pWih, pWhh, gbih, gbhh, pWdyn, bdyn, hist);

    // --- CGConv 1 ---
    proj_mfma<<<(NN+63)/64, 256, 0, stream>>>(hist, P1h, P1l, Af, As, BP);
    cg_agg<<<(NN+3)/4, 256, 0, stream>>>(hist, recS, offv, cnt,
                                         c1Wf,c1bf,c1Ws,c1bs, Af, As, BP,
                                         c1g,c1b,c1m,c1v, f1);

    // --- CGConv 2 ---
    proj_mfma<<<(NN+63)/64, 256, 0, stream>>>(f1, P2h, P2l, Af, As, BP);
    cg_agg<<<(NN+3)/4, 256, 0, stream>>>(f1, recS, offv, cnt,
                                         c2Wf,c2bf,c2Ws,c2bs, Af, As, BP,
                                         c2g,c2b,c2m,c2v, f2);

    // --- target encoding ---
    target_kernel<<<(BB+3)/4, 256, 0, stream>>>(hist, f2, tgt, Wn, bn_, enc);

    // --- LSTM decoder prep (MFMA gi0) ---
    gi0_mfma<<<BB/16, 512, 0, stream>>>(enc, GIh, GIl, l0bih, l0bhh, gi0);

    // --- LSTM decoder (W0/W1 both in registers, 32KB LDS) ---
    lstm_mfma<<<BB/LMB, 512, 0, stream>>>(gi0, B0h, B1h,
                                          l1bih, l1bhh, h1buf);

    // --- out-projection ---
    out_proj<<<(BB*OUTL+255)/256, 256, 0, stream>>>(h1buf, Wop, bop, (float*)d_out);
}

// Round 12
// 573.242 us; speedup vs baseline: 1.0663x; 1.0663x over previous
//
#include <hip/hip_runtime.h>
#include <hip/hip_fp16.h>
#include <math.h>

#define NN   50000
#define TT   16
#define EE   800000
#define BB   2000
#define EMBD 32
#define ENC  64
#define DEC  128
#define OUTL 25
#define BN_EPS 1e-5f

typedef short v8s __attribute__((ext_vector_type(8)));
typedef float v4f __attribute__((ext_vector_type(4)));
#define MFMA16(a,b,c) __builtin_amdgcn_mfma_f32_16x16x32_bf16((a),(b),(c),0,0,0)

__device__ __forceinline__ float lrelu(float v){ return v >= 0.f ? v : 0.1f*v; }
__device__ __forceinline__ float fsig(float v){ return __builtin_amdgcn_rcpf(1.f + __expf(-v)); }
__device__ __forceinline__ float ftanh(float v){ return 2.f*__builtin_amdgcn_rcpf(1.f + __expf(-2.f*v)) - 1.f; }
__device__ __forceinline__ float fsoftplus(float v){
    return v > 15.f ? v : __logf(1.f + __expf(v));
}

__device__ __forceinline__ unsigned short f2bf(float f){
    unsigned u = __float_as_uint(f);
    u = u + 0x7FFFu + ((u>>16)&1u);
    return (unsigned short)(u>>16);
}
__device__ __forceinline__ float bf2f(unsigned short s){ return __uint_as_float(((unsigned)s)<<16); }

// truncation-based hi/lo split (R12)
__device__ __forceinline__ void tsplit(float v, unsigned short& hi, unsigned short& lo){
    unsigned u = __float_as_uint(v);
    hi = (unsigned short)(u >> 16);
    float r = v - __uint_as_float(u & 0xFFFF0000u);
    lo = (unsigned short)(__float_as_uint(r) >> 16);
}

__device__ __forceinline__ v8s as_v8s(int4 v){
    union { int4 i; v8s s; } u; u.i = v; return u.s;
}

__device__ __forceinline__ void cvt8(const float* p, v8s& hi, v8s& lo){
    float4 a0 = *(const float4*)p;
    float4 a1 = *(const float4*)(p+4);
    float av[8] = {a0.x,a0.y,a0.z,a0.w,a1.x,a1.y,a1.z,a1.w};
#pragma unroll
    for (int j=0;j<8;j++){
        unsigned short h = f2bf(av[j]);
        hi[j] = (short)h;
        lo[j] = (short)f2bf(av[j] - bf2f(h));
    }
}
// reconstruct hi+lo, lrelu, re-split
__device__ __forceinline__ void lrelu_resplit(v8s hh, v8s hl, v8s& oh, v8s& ol){
#pragma unroll
    for (int j=0;j<8;j++){
        float v = bf2f((unsigned short)hh[j]) + bf2f((unsigned short)hl[j]);
        float a = lrelu(v);
        unsigned short h = f2bf(a);
        oh[j] = (short)h;
        ol[j] = (short)f2bf(a - bf2f(h));
    }
}

// ---------------- fused packing helpers ----------------
__device__ __forceinline__ void pf_item(const float* W, int K, int KB, int i,
                                        unsigned short* out){
    int l = i & 63, fb = i >> 6;
    int kb = fb % KB, nt = fb / KB;
    int n = nt*16 + (l&15);
    int k0 = kb*32 + ((l>>4)*8);
#pragma unroll
    for (int j=0;j<8;j++) out[i*8+j] = f2bf(W[(size_t)n*K + k0 + j]);
}
__device__ __forceinline__ void phl_item(const float* W, int K, int KB, int i,
                                         unsigned short* hi, unsigned short* lo){
    int l = i & 63, fb = i >> 6;
    int kb = fb % KB, nt = fb / KB;
    int n = nt*16 + (l&15);
    int k0 = kb*32 + ((l>>4)*8);
#pragma unroll
    for (int j=0;j<8;j++){
        float v = W[(size_t)n*K + k0 + j];
        unsigned short h = f2bf(v);
        hi[i*8+j] = h;
        lo[i*8+j] = f2bf(v - bf2f(h));
    }
}
__device__ __forceinline__ void pcat_item(const float* Wa, const float* Wb,
                                          int K1, int K, int KB, int i,
                                          unsigned short* out){
    int l = i & 63, fb = i >> 6;
    int kb = fb % KB, nt = fb / KB;
    int n = nt*16 + (l&15);
    int k0 = kb*32 + ((l>>4)*8);
#pragma unroll
    for (int j=0;j<8;j++){
        int k = k0 + j;
        float v = (k < K1) ? Wa[(size_t)n*K1 + k] : Wb[(size_t)n*(K-K1) + (k-K1)];
        out[i*8+j] = f2bf(v);
    }
}
__device__ __forceinline__ void pproj_item(const float* Wf, const float* Ws, int i,
                                           unsigned short* hi, unsigned short* lo){
    int l = i & 63, fb = i >> 6;
    int kb = fb & 1, nt = fb >> 1;
    int n = nt*16 + (l&15);
    int d = n >> 6, c = n & 63;
    const float* W = (d < 2) ? Wf : Ws;
    int k0 = (d&1)*64 + kb*32 + ((l>>4)*8);
#pragma unroll
    for (int j=0;j<8;j++){
        float v = W[c*130 + k0 + j];
        unsigned short h = f2bf(v);
        hi[i*8+j] = h;
        lo[i*8+j] = f2bf(v - bf2f(h));
    }
}

// ---------------- all weight prep in ONE dispatch ----------------
__global__ void pack_all(
    const float* __restrict__ gWih, const float* __restrict__ gWhh,
    const float* __restrict__ Wdyn,
    const float* __restrict__ l0Whh, const float* __restrict__ l1Wih,
    const float* __restrict__ l1Whh, const float* __restrict__ l0Wih,
    const float* __restrict__ c1Wf, const float* __restrict__ c1Ws,
    const float* __restrict__ c2Wf, const float* __restrict__ c2Ws,
    unsigned short* __restrict__ pWih, unsigned short* __restrict__ pWhh,
    unsigned short* __restrict__ pWdyn,
    unsigned short* __restrict__ B0h, unsigned short* __restrict__ B1h,
    unsigned short* __restrict__ P1h, unsigned short* __restrict__ P1l,
    unsigned short* __restrict__ P2h, unsigned short* __restrict__ P2l,
    unsigned short* __restrict__ GIh, unsigned short* __restrict__ GIl,
    int* __restrict__ cnt, int* __restrict__ gtot)
{
    int i = blockIdx.x*256 + threadIdx.x;
    if (i < 768){ pf_item(gWih, 32, 1, i, pWih); return; }   i -= 768;
    if (i < 1536){ pf_item(gWhh, 64, 2, i, pWhh); return; }  i -= 1536;
    if (i < 512){ pf_item(Wdyn, 64, 2, i, pWdyn); return; }  i -= 512;
    if (i < 8192){ pcat_item(l0Whh, l0Whh, 128, 128, 4, i, B0h); return; } i -= 8192;
    if (i < 16384){ pcat_item(l1Wih, l1Whh, 128, 256, 8, i, B1h); return; } i -= 16384;
    if (i < 2048){ pproj_item(c1Wf, c1Ws, i, P1h, P1l); return; } i -= 2048;
    if (i < 2048){ pproj_item(c2Wf, c2Ws, i, P2h, P2l); return; } i -= 2048;
    if (i < 8192){ phl_item(l0Wih, 128, 4, i, GIh, GIl); return; } i -= 8192;
    if (i < NN){ cnt[i] = 0; return; } i -= NN;
    if (i < 1){ gtot[0] = 0; return; }
}
#define PACK_TOTAL (768+1536+512+8192+16384+2048+2048+8192+NN+1)

// ---------------- GRU encoder v12 (unchanged) ----------------
__global__ __launch_bounds__(256) void encoder_mfma(
    const float* __restrict__ x,
    const float* __restrict__ Wip, const float* __restrict__ bip,
    const unsigned short* __restrict__ pWih,
    const unsigned short* __restrict__ pWhh,
    const float* __restrict__ bih, const float* __restrict__ bhh,
    const unsigned short* __restrict__ pWdyn,
    const float* __restrict__ bdyn,
    float* __restrict__ hist)
{
    __shared__ unsigned short efh[4*512], efl[4*512];          // e A-frags, 4-step window
    __shared__ unsigned short hfh[2][1024], hfl[2][1024];      // dbuf h A-frags (swizzled)
    const int tid = threadIdx.x;
    const int l   = tid & 63;
    const int w   = tid >> 6;          // wave owns g-tile w
    const int ln  = l & 15, q = l >> 4;
    const int blk = blockIdx.x;
    const int rsw = ((l>>1)&7)<<3;     // read swizzle key

    for (int i = tid; i < 1024; i += 256){
        hfh[0][i]=0; hfl[0][i]=0; hfh[1][i]=0; hfl[1][i]=0;
    }

    // e-compute decomposition: thread owns ONE k (3 weight regs) + 2 nodes
    const int k0 = tid & 31;
    const int mb = tid >> 5;           // nodes 2mb, 2mb+1
    const float ew0 = Wip[2*k0], ew1 = Wip[2*k0+1], ebk = bip[k0];
    const int ebase = (k0>>3)*128 + (k0&7);
    const float2* xr0 = (const float2*)(x + (size_t)(blk*16 + 2*mb    )*32);
    const float2* xr1 = (const float2*)(x + (size_t)(blk*16 + 2*mb + 1)*32);

    const int c = w*16 + ln;
    const float bR  = bih[c]       + bhh[c];
    const float bZ  = bih[64 + c]  + bhh[64 + c];
    const float bNI = bih[128 + c];
    const float bNH = bhh[128 + c];
    float hprev[4] = {0.f,0.f,0.f,0.f};

    const v8s* FIH = (const v8s*)pWih;
    const v8s* FHH = (const v8s*)pWhh;
    const v8s* FDY = (const v8s*)pWdyn;
    const int wbase = (c>>5)*512 + (16*((c&31)>>3))*8 + (c&7);
    __syncthreads();                   // h zero-init ready

    int p = 0;
#pragma unroll 1
    for (int tb = 0; tb < 4; tb++){
#pragma unroll
        for (int ts = 0; ts < 4; ts++){
            int t = tb*4 + ts;
            float2 xv0 = xr0[t], xv1 = xr1[t];
            float e0 = lrelu(ew0*xv0.x + ew1*xv0.y + ebk);
            float e1 = lrelu(ew0*xv1.x + ew1*xv1.y + ebk);
            unsigned short h_, l_;
            tsplit(e0, h_, l_);
            efh[ts*512 + ebase + (2*mb  )*8] = h_;
            efl[ts*512 + ebase + (2*mb  )*8] = l_;
            tsplit(e1, h_, l_);
            efh[ts*512 + ebase + (2*mb+1)*8] = h_;
            efl[ts*512 + ebase + (2*mb+1)*8] = l_;
        }
        __syncthreads();               // ef window ready
#pragma unroll 1
        for (int ts = 0; ts < 4; ts++){
            v8s eh  = *(const v8s*)&efh[ts*512 + l*8];
            v8s el  = *(const v8s*)&efl[ts*512 + l*8];
            v8s h0h = *(const v8s*)&hfh[p][(l*8) ^ rsw];
            v8s h0l = *(const v8s*)&hfl[p][(l*8) ^ rsw];
            v8s h1h = *(const v8s*)&hfh[p][512 + ((l*8) ^ rsw)];
            v8s h1l = *(const v8s*)&hfl[p][512 + ((l*8) ^ rsw)];

            v4f aR = {bR,bR,bR,bR};
            v4f aZ = {bZ,bZ,bZ,bZ};
            v4f aNI= {bNI,bNI,bNI,bNI};
            v4f aNH= {bNH,bNH,bNH,bNH};
            v8s b;
            b = FIH[(w   )*64 + l];    aR = MFMA16(eh,b,aR);  aR = MFMA16(el,b,aR);
            b = FHH[(w*2+0)*64+l];     aR = MFMA16(h0h,b,aR); aR = MFMA16(h0l,b,aR);
            b = FHH[(w*2+1)*64+l];     aR = MFMA16(h1h,b,aR); aR = MFMA16(h1l,b,aR);
            b = FIH[(4+w )*64 + l];    aZ = MFMA16(eh,b,aZ);  aZ = MFMA16(el,b,aZ);
            b = FHH[((4+w)*2+0)*64+l]; aZ = MFMA16(h0h,b,aZ); aZ = MFMA16(h0l,b,aZ);
            b = FHH[((4+w)*2+1)*64+l]; aZ = MFMA16(h1h,b,aZ); aZ = MFMA16(h1l,b,aZ);
            b = FIH[(8+w )*64 + l];    aNI= MFMA16(eh,b,aNI); aNI= MFMA16(el,b,aNI);
            b = FHH[((8+w)*2+0)*64+l]; aNH= MFMA16(h0h,b,aNH);aNH= MFMA16(h0l,b,aNH);
            b = FHH[((8+w)*2+1)*64+l]; aNH= MFMA16(h1h,b,aNH);aNH= MFMA16(h1l,b,aNH);

#pragma unroll
            for (int i = 0; i < 4; i++){
                float r_ = fsig(aR[i]);
                float z_ = fsig(aZ[i]);
                float nn_ = ftanh(aNI[i] + r_*aNH[i]);
                float hn = nn_ + z_*(hprev[i] - nn_);
                hprev[i] = hn;
                int row = q*4 + i;
                int off = (wbase + row*8) ^ ((((row)>>1)&7)<<3);
                unsigned short hh_, hl_;
                tsplit(hn, hh_, hl_);
                hfh[1-p][off] = hh_;
                hfl[1-p][off] = hl_;
            }
            __syncthreads();   // per-step barrier
            p ^= 1;
        }
    }
    {
        v8s a0h,a0l,a1h,a1l;
        lrelu_resplit(*(const v8s*)&hfh[p][(l*8) ^ rsw],
                      *(const v8s*)&hfl[p][(l*8) ^ rsw],       a0h, a0l);
        lrelu_resplit(*(const v8s*)&hfh[p][512 + ((l*8) ^ rsw)],
                      *(const v8s*)&hfl[p][512 + ((l*8) ^ rsw)], a1h, a1l);
        const int nt = w;
        float bb = bdyn[nt*16 + ln];
        v4f acc = {bb,bb,bb,bb};
        v8s b;
        b = FDY[(nt*2+0)*64 + l]; acc = MFMA16(a0h,b,acc); acc = MFMA16(a0l,b,acc);
        b = FDY[(nt*2+1)*64 + l]; acc = MFMA16(a1h,b,acc); acc = MFMA16(a1l,b,acc);
#pragma unroll
        for (int i = 0; i < 4; i++){
            hist[(size_t)(blk*16 + q*4 + i)*64 + nt*16 + ln] = lrelu(acc[i]);
        }
    }
}

// ---------------- CGConv projections v2: f16-packed B-gates (unchanged) ----------------
#define PROJ_ACC(NT, ACC) { \
    v8s bh0_ = FH[((NT)*2+0)*64 + l], bl0_ = FL[((NT)*2+0)*64 + l]; \
    v8s bh1_ = FH[((NT)*2+1)*64 + l], bl1_ = FL[((NT)*2+1)*64 + l]; \
    ACC = MFMA16(ah0,bh0_,ACC); ACC = MFMA16(al0,bh0_,ACC); ACC = MFMA16(ah0,bl0_,ACC); \
    ACC = MFMA16(ah1,bh1_,ACC); ACC = MFMA16(al1,bh1_,ACC); ACC = MFMA16(ah1,bl1_,ACC); }

__global__ __launch_bounds__(256) void proj_mfma(
    const float* __restrict__ xin,
    const unsigned short* __restrict__ Bh, const unsigned short* __restrict__ Bl,
    float* __restrict__ Af, float* __restrict__ As,
    unsigned* __restrict__ BP)
{
    __shared__ float sx[64*68];
    const int tid = threadIdx.x;
    const int l = tid & 63;
    const int w = tid >> 6;
    const int ln = l & 15, q = l >> 4;
    const int n0 = blockIdx.x*64;

    for (int i=tid;i<64*16;i+=256){
        int nn = i>>4, f4 = i&15;
        float4 v = {0.f,0.f,0.f,0.f};
        if (n0+nn < NN) v = ((const float4*)(xin + (size_t)(n0+nn)*64))[f4];
        *(float4*)&sx[nn*68 + f4*4] = v;
    }
    __syncthreads();

    v8s ah0,al0,ah1,al1;
    cvt8(&sx[(w*16+ln)*68 +      q*8], ah0, al0);
    cvt8(&sx[(w*16+ln)*68 + 32 + q*8], ah1, al1);

    const v8s* FH = (const v8s*)Bh;
    const v8s* FL = (const v8s*)Bl;
#pragma unroll 1
    for (int c3=0; c3<4; c3++){
        v4f aA = {0.f,0.f,0.f,0.f};
        v4f aS = aA, aF = aA, aB = aA;
        PROJ_ACC(c3,      aA);
        PROJ_ACC(8 + c3,  aS);
        PROJ_ACC(4 + c3,  aF);
        PROJ_ACC(12 + c3, aB);
        int col = c3*16 + ln;
#pragma unroll
        for (int i=0;i<4;i++){
            int node = n0 + w*16 + q*4 + i;
            if (node < NN){
                Af[(size_t)node*64 + col] = aA[i];
                As[(size_t)node*64 + col] = aS[i];
                unsigned pf = __half_as_ushort(__float2half(aF[i]));
                unsigned ps = __half_as_ushort(__float2half(aB[i]));
                BP[(size_t)node*64 + col] = pf | (ps << 16);
            }
        }
    }
}

// ---------------- dst segment build: histogram + atomic alloc + scatter ----------------
__global__ void count_kernel(const int* __restrict__ ei, int* __restrict__ cnt){
    int e = blockIdx.x*256 + threadIdx.x;
    if (e < EE) atomicAdd(&cnt[ei[EE+e]], 1);
}

__global__ void alloc_kernel(const int* __restrict__ cnt, int* __restrict__ gtot,
                             int* __restrict__ off, int* __restrict__ cur){
    int n = blockIdx.x*256 + threadIdx.x;
    if (n >= NN) return;
    int c = cnt[n];
    int s = atomicAdd(gtot, c);
    off[n] = s;
    cur[n] = s;
}

// scatter: 8-byte records {src:int, ea:2xf16}
__global__ void scatter_kernel(const int* __restrict__ ei, const float* __restrict__ ea,
                               int* __restrict__ cur, int2* __restrict__ recS){
    int e = blockIdx.x*256 + threadIdx.x;
    if (e >= EE) return;
    int d = ei[EE+e];
    int p = atomicAdd(&cur[d], 1);
    unsigned e0 = __half_as_ushort(__float2half(ea[2*(size_t)e]));
    unsigned e1 = __half_as_ushort(__float2half(ea[2*(size_t)e+1]));
    int2 r;
    r.x = ei[e];
    r.y = (int)(e0 | (e1 << 16));
    recS[p] = r;
}

// ---------------- CGConv aggregate: 8B records + f16 B-gate gather ----------------
__global__ __launch_bounds__(256) void cg_agg(
    const float* __restrict__ xin,
    const int2* __restrict__ recS,
    const int* __restrict__ off, const int* __restrict__ cnt,
    const float* __restrict__ Wf, const float* __restrict__ bf,
    const float* __restrict__ Ws, const float* __restrict__ bs,
    const float* __restrict__ Af, const float* __restrict__ As,
    const unsigned* __restrict__ BP,
    const float* __restrict__ gamma, const float* __restrict__ beta,
    const float* __restrict__ mean, const float* __restrict__ var,
    float* __restrict__ outp)
{
    const int tid = threadIdx.x;
    const int c = tid & 63, wid = tid >> 6;
    const int n = blockIdx.x*4 + wid;
    if (n >= NN) return;

    const float wf0 = Wf[c*130+128], wf1 = Wf[c*130+129], bfc = bf[c];
    const float ws0 = Ws[c*130+128], ws1 = Ws[c*130+129], bsc = bs[c];
    const float afd = Af[(size_t)n*64+c] + bfc, asd = As[(size_t)n*64+c] + bsc;
    const unsigned* BPc = BP + c;

    float acc = 0.f;
    int i = off[n];
    const int i1 = i + cnt[n];
#pragma unroll 1
    for (; i+1 < i1; i += 2){
        int2 r0 = recS[i], r1 = recS[i+1];
        unsigned ea0 = (unsigned)r0.y, ea1 = (unsigned)r1.y;
        float e00 = __half2float(__ushort_as_half((unsigned short)(ea0 & 0xFFFFu)));
        float e01 = __half2float(__ushort_as_half((unsigned short)(ea0 >> 16)));
        float e10 = __half2float(__ushort_as_half((unsigned short)(ea1 & 0xFFFFu)));
        float e11 = __half2float(__ushort_as_half((unsigned short)(ea1 >> 16)));
        unsigned pv0 = BPc[(size_t)r0.x*64];
        unsigned pv1 = BPc[(size_t)r1.x*64];
        float bf0v = __half2float(__ushort_as_half((unsigned short)(pv0 & 0xFFFFu)));
        float bs0v = __half2float(__ushort_as_half((unsigned short)(pv0 >> 16)));
        float bf1v = __half2float(__ushort_as_half((unsigned short)(pv1 & 0xFFFFu)));
        float bs1v = __half2float(__ushort_as_half((unsigned short)(pv1 >> 16)));
        float gf0 = afd + bf0v + wf0*e00 + wf1*e01;
        float gs0 = asd + bs0v + ws0*e00 + ws1*e01;
        float gf1 = afd + bf1v + wf0*e10 + wf1*e11;
        float gs1 = asd + bs1v + ws0*e10 + ws1*e11;
        acc += fsig(gf0)*fsoftplus(gs0);
        acc += fsig(gf1)*fsoftplus(gs1);
    }
    if (i < i1){
        int2 r0 = recS[i];
        unsigned ea0 = (unsigned)r0.y;
        float e00 = __half2float(__ushort_as_half((unsigned short)(ea0 & 0xFFFFu)));
        float e01 = __half2float(__ushort_as_half((unsigned short)(ea0 >> 16)));
        unsigned pv0 = BPc[(size_t)r0.x*64];
        float bf0v = __half2float(__ushort_as_half((unsigned short)(pv0 & 0xFFFFu)));
        float bs0v = __half2float(__ushort_as_half((unsigned short)(pv0 >> 16)));
        float gf = afd + bf0v + wf0*e00 + wf1*e01;
        float gs = asd + bs0v + ws0*e00 + ws1*e01;
        acc += fsig(gf)*fsoftplus(gs);
    }
    float bn = (acc - mean[c])*rsqrtf(var[c]+BN_EPS)*gamma[c] + beta[c];
    outp[(size_t)n*64+c] = xin[(size_t)n*64+c] + bn;
}

// ---------------- target gather + nbrs linear + concat (unchanged) ----------------
__global__ __launch_bounds__(256) void target_kernel(
    const float* __restrict__ hist, const float* __restrict__ f2,
    const int* __restrict__ tgt,
    const float* __restrict__ Wn, const float* __restrict__ bn_,
    float* __restrict__ enc)
{
    const int tid=threadIdx.x;
    const int c = tid&63, q = tid>>6;
    const int b = blockIdx.x*4 + q;
    if (b>=BB) return;
    const int n = tgt[b];
    float a = bn_[c];
#pragma unroll
    for (int k=0;k<ENC;k++) a += Wn[c*64+k]*f2[(size_t)n*64+k];
    enc[(size_t)b*128 + 64 + c] = lrelu(a);
    enc[(size_t)b*128 + c]      = hist[(size_t)n*64+c];
}

// ---------------- gi0 via MFMA (unchanged) ----------------
__global__ __launch_bounds__(512) void gi0_mfma(
    const float* __restrict__ enc,
    const unsigned short* __restrict__ GIh, const unsigned short* __restrict__ GIl,
    const float* __restrict__ bih0, const float* __restrict__ bhh0,
    float* __restrict__ gi0)
{
    __shared__ float senc[16*132];
    const int tid = threadIdx.x;
    const int l = tid & 63;
    const int w = tid >> 6;
    const int ln = l & 15, q = l >> 4;
    const int b0 = blockIdx.x*16;

    for (int i=tid;i<16*32;i+=512){
        int row = i>>5, f4 = i&31;
        *(float4*)&senc[row*132 + f4*4] = ((const float4*)(enc + (size_t)(b0+row)*128))[f4];
    }
    __syncthreads();

    v8s ah[4], al[4];
#pragma unroll
    for (int kb=0;kb<4;kb++) cvt8(&senc[ln*132 + kb*32 + q*8], ah[kb], al[kb]);

    const v8s* FH = (const v8s*)GIh;
    const v8s* FL = (const v8s*)GIl;
#pragma unroll
    for (int u=0;u<4;u++){
        int nt = w*4 + u;
        int col = nt*16 + ln;
        float bb = bih0[col] + bhh0[col];
        v4f acc = {bb,bb,bb,bb};
#pragma unroll
        for (int kb=0;kb<4;kb++){
            v8s bh = FH[(nt*4+kb)*64 + l];
            v8s bl = FL[(nt*4+kb)*64 + l];
            acc = MFMA16(ah[kb],bh,acc); acc = MFMA16(al[kb],bh,acc); acc = MFMA16(ah[kb],bl,acc);
        }
#pragma unroll
        for (int i=0;i<4;i++)
            gi0[(size_t)(b0 + q*4 + i)*512 + col] = acc[i];
    }
}

// ---------------- 2-layer LSTM decoder (R10 version: sW0 in LDS, W1r in regs) ----------------
// R24 post-mortem of R11's W0r hoist: W0r(64)+W1r(128)+state ~260 > 256 ->
// scratch spill (FETCH 3.6->8.85MB, dur 85->121us). REVERTED to sW0-in-LDS.
// The LSTM register file is full; W1r is the most that fits.
#define LMB 16
__global__ __launch_bounds__(512)
__attribute__((amdgpu_waves_per_eu(2,2)))
void lstm_mfma(
    const float* __restrict__ gi0,
    const unsigned short* __restrict__ B0h,
    const unsigned short* __restrict__ B1h,
    const float* __restrict__ bih1, const float* __restrict__ bhh1,
    float* __restrict__ h1buf)
{
    __shared__ int4 sW0[32*4*64];                                // 131072 B
    __shared__ unsigned short h0hi[2][4*512], h0lo[2][4*512];    // 16384 B
    __shared__ unsigned short h1hi[2][4*512], h1lo[2][4*512];    // 16384 B
    const int tid = threadIdx.x;
    const int l = tid & 63;
    const int w = tid >> 6;
    const int c = l & 15;
    const int q = l >> 4;
    const int j = w*16 + c;
    const int b0 = blockIdx.x*LMB;
    const int lsw = ((l>>1)&7)<<3;     // read swizzle key (row = l)

    {
        const int4* F0 = (const int4*)B0h;
        for (int i=tid;i<32*4*64;i+=512) sW0[i] = F0[i];
    }
    for (int i=tid;i<4*512;i+=512){
        h0hi[0][i]=0; h0lo[0][i]=0; h0hi[1][i]=0; h0lo[1][i]=0;
        h1hi[0][i]=0; h1lo[0][i]=0; h1hi[1][i]=0; h1lo[1][i]=0;
    }

    int4 W1r[32];
    {
        const int4* F1 = (const int4*)B1h;
#pragma unroll
        for (int g=0;g<4;g++)
#pragma unroll
            for (int kb=0;kb<8;kb++) W1r[g*8+kb] = F1[((g*8+w)*8 + kb)*64 + l];
#pragma unroll
        for (int i=0;i<32;i++)
            asm volatile("" : "+v"(W1r[i].x), "+v"(W1r[i].y), "+v"(W1r[i].z), "+v"(W1r[i].w));
    }

    float rgi[4][4];
#pragma unroll
    for (int g=0;g<4;g++)
#pragma unroll
        for (int i=0;i<4;i++)
            rgi[g][i] = gi0[(size_t)(b0 + q*4 + i)*512 + g*128 + j];

    float b1[4];
#pragma unroll
    for (int g=0;g<4;g++) b1[g] = bih1[g*128+j] + bhh1[g*128+j];
    float c0[4] = {0,0,0,0}, c1[4] = {0,0,0,0};
    const int kbw = j>>5, qw = (j>>3)&3, jw = j&7;
    __syncthreads();

    int p = 0;
#pragma unroll 1
    for (int t=0;t<OUTL;t++){
        // ---- layer 0: read h0[p], write h0[1-p]; dual hi/lo accumulators ----
        v4f aH[4], aL[4];
#pragma unroll
        for (int g=0;g<4;g++){
            v4f t4 = {rgi[g][0], rgi[g][1], rgi[g][2], rgi[g][3]};
            aH[g] = t4;
            v4f z = {0.f,0.f,0.f,0.f};
            aL[g] = z;
        }
#pragma unroll
        for (int kb=0;kb<4;kb++){
            v8s ah = *(const v8s*)&h0hi[p][kb*512 + ((l*8) ^ lsw)];
            v8s al = *(const v8s*)&h0lo[p][kb*512 + ((l*8) ^ lsw)];
#pragma unroll
            for (int g=0;g<4;g++){
                v8s bfr = as_v8s(sW0[((g*8+w)*4 + kb)*64 + l]);
                aH[g] = MFMA16(ah, bfr, aH[g]);
                aL[g] = MFMA16(al, bfr, aL[g]);
            }
        }
#pragma unroll
        for (int i=0;i<4;i++){
            float gi_ = aH[0][i]+aL[0][i], gf_ = aH[1][i]+aL[1][i];
            float gg_ = aH[2][i]+aL[2][i], go_ = aH[3][i]+aL[3][i];
            c0[i] = fsig(gf_)*c0[i] + fsig(gi_)*ftanh(gg_);
            float hn = fsig(go_)*ftanh(c0[i]);
            int row = q*4 + i;
            int off = (kbw*512 + (qw*16 + row)*8 + jw) ^ (((row>>1)&7)<<3);
            unsigned short h = f2bf(hn);
            h0hi[1-p][off] = h;
            h0lo[1-p][off] = f2bf(hn - bf2f(h));
        }
        __syncthreads();   // B1: the ONLY barrier per step

        // ---- layer 1: read h0[1-p] + h1[p], write h1[1-p] ----
        v4f bH[4], bL[4];
#pragma unroll
        for (int g=0;g<4;g++){
            v4f t4={b1[g],b1[g],b1[g],b1[g]}; bH[g]=t4;
            v4f z={0.f,0.f,0.f,0.f}; bL[g]=z;
        }
#pragma unroll
        for (int kb=0;kb<8;kb++){
            const unsigned short* hb = (kb<4) ? h0hi[1-p] : h1hi[p];
            const unsigned short* lb = (kb<4) ? h0lo[1-p] : h1lo[p];
            int kk = kb & 3;
            v8s ah = *(const v8s*)&hb[kk*512 + ((l*8) ^ lsw)];
            v8s al = *(const v8s*)&lb[kk*512 + ((l*8) ^ lsw)];
#pragma unroll
            for (int g=0;g<4;g++){
                bH[g] = MFMA16(ah, as_v8s(W1r[g*8+kb]), bH[g]);
                bL[g] = MFMA16(al, as_v8s(W1r[g*8+kb]), bL[g]);
            }
        }
        float h1new[4];
#pragma unroll
        for (int i=0;i<4;i++){
            float gi_ = bH[0][i]+bL[0][i], gf_ = bH[1][i]+bL[1][i];
            float gg_ = bH[2][i]+bL[2][i], go_ = bH[3][i]+bL[3][i];
            c1[i] = fsig(gf_)*c1[i] + fsig(gi_)*ftanh(gg_);
            h1new[i] = fsig(go_)*ftanh(c1[i]);
            int row = q*4 + i;
            int off = (kbw*512 + (qw*16 + row)*8 + jw) ^ (((row>>1)&7)<<3);
            unsigned short h = f2bf(h1new[i]);
            h1hi[1-p][off] = h;
            h1lo[1-p][off] = f2bf(h1new[i] - bf2f(h));
        }

        // ---- out-proj deferred: stream h1 (f32) to global scratch ----
#pragma unroll
        for (int i=0;i<4;i++){
            h1buf[((size_t)(b0 + q*4 + i)*OUTL + t)*DEC + j] = h1new[i];
        }
        p ^= 1;
    }
}

// ---------------- out-projection: fut = h1buf @ Wop^T + bop (unchanged) ----------------
__global__ __launch_bounds__(256) void out_proj(
    const float* __restrict__ h1buf,
    const float* __restrict__ Wop, const float* __restrict__ bop,
    float* __restrict__ outp)
{
    int idx = blockIdx.x*256 + threadIdx.x;      // idx = b*OUTL + t
    if (idx >= BB*OUTL) return;
    const float4* hp = (const float4*)(h1buf + (size_t)idx*DEC);
    const float4* w0 = (const float4*)Wop;
    const float4* w1 = (const float4*)(Wop + DEC);
    float a0 = 0.f, a1 = 0.f;
#pragma unroll
    for (int k=0;k<32;k++){
        float4 h = hp[k], x0 = w0[k], x1 = w1[k];
        a0 += h.x*x0.x + h.y*x0.y + h.z*x0.z + h.w*x0.w;
        a1 += h.x*x1.x + h.y*x1.y + h.z*x1.z + h.w*x1.w;
    }
    outp[(size_t)idx*2    ] = a0 + bop[0];
    outp[(size_t)idx*2 + 1] = a1 + bop[1];
}

extern "C" void kernel_launch(void* const* d_in, const int* in_sizes, int n_in,
                              void* d_out, int out_size, void* d_ws, size_t ws_size,
                              hipStream_t stream)
{
    const float* x    = (const float*)d_in[0];
    const int*   ei   = (const int*)d_in[1];
    const float* ea   = (const float*)d_in[2];
    const int*   tgt  = (const int*)d_in[3];
    const float* Wip  = (const float*)d_in[4];
    const float* bip  = (const float*)d_in[5];
    const float* gWih = (const float*)d_in[6];
    const float* gWhh = (const float*)d_in[7];
    const float* gbih = (const float*)d_in[8];
    const float* gbhh = (const float*)d_in[9];
    const float* Wdyn = (const float*)d_in[10];
    const float* bdyn = (const float*)d_in[11];
    const float* c1Wf=(const float*)d_in[12]; const float* c1bf=(const float*)d_in[13];
    const float* c1Ws=(const float*)d_in[14]; const float* c1bs=(const float*)d_in[15];
    const float* c1g =(const float*)d_in[16]; const float* c1b =(const float*)d_in[17];
    const float* c1m =(const float*)d_in[18]; const float* c1v =(const float*)d_in[19];
    const float* c2Wf=(const float*)d_in[20]; const float* c2bf=(const float*)d_in[21];
    const float* c2Ws=(const float*)d_in[22]; const float* c2bs=(const float*)d_in[23];
    const float* c2g =(const float*)d_in[24]; const float* c2b =(const float*)d_in[25];
    const float* c2m =(const float*)d_in[26]; const float* c2v =(const float*)d_in[27];
    const float* Wn  =(const float*)d_in[28]; const float* bn_ =(const float*)d_in[29];
    const float* l0Wih=(const float*)d_in[30]; const float* l0Whh=(const float*)d_in[31];
    const float* l0bih=(const float*)d_in[32]; const float* l0bhh=(const float*)d_in[33];
    const float* l1Wih=(const float*)d_in[34]; const float* l1Whh=(const float*)d_in[35];
    const float* l1bih=(const float*)d_in[36]; const float* l1bhh=(const float*)d_in[37];
    const float* Wop =(const float*)d_in[38]; const float* bop=(const float*)d_in[39];

    float* ws = (float*)d_ws;
    size_t o = 0;
    float* hist = ws + o; o += (size_t)NN*ENC;
    float* f1   = ws + o; o += (size_t)NN*ENC;
    float* f2   = ws + o; o += (size_t)NN*ENC;
    float* Af   = ws + o; o += (size_t)NN*ENC;
    float* Bfs  = ws + o; o += (size_t)NN*ENC;   // BP slot (u32 packed B-gates)
    float* As   = ws + o; o += (size_t)NN*ENC;
    float* enc  = ws + o; o += (size_t)BB*2*ENC;
    float* gi0  = ws + o; o += (size_t)BB*4*DEC;
    unsigned short* pWih  = (unsigned short*)(ws + o); o += (size_t)12*64*8/2;
    unsigned short* pWhh  = (unsigned short*)(ws + o); o += (size_t)24*64*8/2;
    unsigned short* pWdyn = (unsigned short*)(ws + o); o += (size_t)8*64*8/2;
    unsigned short* B0h = (unsigned short*)(ws + o); o += (size_t)32*4*64*8/2;
    unsigned short* B1h = (unsigned short*)(ws + o); o += (size_t)32*8*64*8/2;
    unsigned short* P1h = (unsigned short*)(ws + o); o += (size_t)2048*8/2;
    unsigned short* P1l = (unsigned short*)(ws + o); o += (size_t)2048*8/2;
    unsigned short* P2h = (unsigned short*)(ws + o); o += (size_t)2048*8/2;
    unsigned short* P2l = (unsigned short*)(ws + o); o += (size_t)2048*8/2;
    unsigned short* GIh = (unsigned short*)(ws + o); o += (size_t)8192*8/2;
    unsigned short* GIl = (unsigned short*)(ws + o); o += (size_t)8192*8/2;
    int* cnt    = (int*)(ws + o); o += NN;
    int* offv   = (int*)(ws + o); o += NN+1;
    int* curv   = (int*)(ws + o); o += NN;
    int* gtot   = (int*)(ws + o); o += 1;
    o = (o + 3) & ~(size_t)3;               // align for int2 records
    int2* recS  = (int2*)(ws + o); o += (size_t)2*EE;

    unsigned* BP = (unsigned*)Bfs;

    // h1buf (BB*OUTL*DEC = 6.4M floats) aliases Af..Bfs (2*NN*ENC = 6.4M
    // floats): both dead after cg_agg #2 (stream-ordered before lstm_mfma).
    float* h1buf = Af;

    // --- all weight prep + cnt/gtot zero in one dispatch ---
    pack_all<<<(PACK_TOTAL+255)/256, 256, 0, stream>>>(
        gWih, gWhh, Wdyn, l0Whh, l1Wih, l1Whh, l0Wih,
        c1Wf, c1Ws, c2Wf, c2Ws,
        pWih, pWhh, pWdyn, B0h, B1h, P1h, P1l, P2h, P2l, GIh, GIl, cnt, gtot);

    // --- dst segment build (order-free atomic allocation) ---
    count_kernel<<<(EE+255)/256, 256, 0, stream>>>(ei, cnt);
    alloc_kernel<<<(NN+255)/256, 256, 0, stream>>>(cnt, gtot, offv, curv);
    scatter_kernel<<<(EE+255)/256, 256, 0, stream>>>(ei, ea, curv, recS);

    // --- history encoder (MFMA) ---
    encoder_mfma<<<NN/16, 256, 0, stream>>>(x, Wip, bip, pWih, pWhh, gbih, gbhh, pWdyn, bdyn, hist);

    // --- CGConv 1 ---
    proj_mfma<<<(NN+63)/64, 256, 0, stream>>>(hist, P1h, P1l, Af, As, BP);
    cg_agg<<<(NN+3)/4, 256, 0, stream>>>(hist, recS, offv, cnt,
                                         c1Wf,c1bf,c1Ws,c1bs, Af, As, BP,
                                         c1g,c1b,c1m,c1v, f1);

    // --- CGConv 2 ---
    proj_mfma<<<(NN+63)/64, 256, 0, stream>>>(f1, P2h, P2l, Af, As, BP);
    cg_agg<<<(NN+3)/4, 256, 0, stream>>>(f1, recS, offv, cnt,
                                         c2Wf,c2bf,c2Ws,c2bs, Af, As, BP,
                                         c2g,c2b,c2m,c2v, f2);

    // --- target encoding ---
    target_kernel<<<(BB+3)/4, 256, 0, stream>>>(hist, f2, tgt, Wn, bn_, enc);

    // --- LSTM decoder prep (MFMA gi0) ---
    gi0_mfma<<<BB/16, 512, 0, stream>>>(enc, GIh, GIl, l0bih, l0bhh, gi0);

    // --- LSTM decoder (sW0 in LDS, W1r in regs) ---
    lstm_mfma<<<BB/LMB, 512, 0, stream>>>(gi0, B0h, B1h,
                                          l1bih, l1bhh, h1buf);

    // --- out-projection ---
    out_proj<<<(BB*OUTL+255)/256, 256, 0, stream>>>(h1buf, Wop, bop, (float*)d_out);
}

// Round 13
// 540.765 us; speedup vs baseline: 1.1304x; 1.0601x over previous
//
#include <hip/hip_runtime.h>
#include <hip/hip_fp16.h>
#include <math.h>

#define NN   50000
#define TT   16
#define EE   800000
#define BB   2000
#define EMBD 32
#define ENC  64
#define DEC  128
#define OUTL 25
#define BN_EPS 1e-5f

typedef short v8s __attribute__((ext_vector_type(8)));
typedef float v4f __attribute__((ext_vector_type(4)));
#define MFMA16(a,b,c) __builtin_amdgcn_mfma_f32_16x16x32_bf16((a),(b),(c),0,0,0)

__device__ __forceinline__ float lrelu(float v){ return v >= 0.f ? v : 0.1f*v; }
__device__ __forceinline__ float fsig(float v){ return __builtin_amdgcn_rcpf(1.f + __expf(-v)); }
__device__ __forceinline__ float ftanh(float v){ return 2.f*__builtin_amdgcn_rcpf(1.f + __expf(-2.f*v)) - 1.f; }
__device__ __forceinline__ float fsoftplus(float v){
    return v > 15.f ? v : __logf(1.f + __expf(v));
}

__device__ __forceinline__ unsigned short f2bf(float f){
    unsigned u = __float_as_uint(f);
    u = u + 0x7FFFu + ((u>>16)&1u);
    return (unsigned short)(u>>16);
}
__device__ __forceinline__ float bf2f(unsigned short s){ return __uint_as_float(((unsigned)s)<<16); }

// truncation-based hi/lo split (R12)
__device__ __forceinline__ void tsplit(float v, unsigned short& hi, unsigned short& lo){
    unsigned u = __float_as_uint(v);
    hi = (unsigned short)(u >> 16);
    float r = v - __uint_as_float(u & 0xFFFF0000u);
    lo = (unsigned short)(__float_as_uint(r) >> 16);
}

__device__ __forceinline__ v8s as_v8s(int4 v){
    union { int4 i; v8s s; } u; u.i = v; return u.s;
}

__device__ __forceinline__ void cvt8(const float* p, v8s& hi, v8s& lo){
    float4 a0 = *(const float4*)p;
    float4 a1 = *(const float4*)(p+4);
    float av[8] = {a0.x,a0.y,a0.z,a0.w,a1.x,a1.y,a1.z,a1.w};
#pragma unroll
    for (int j=0;j<8;j++){
        unsigned short h = f2bf(av[j]);
        hi[j] = (short)h;
        lo[j] = (short)f2bf(av[j] - bf2f(h));
    }
}
// reconstruct hi+lo, lrelu, re-split
__device__ __forceinline__ void lrelu_resplit(v8s hh, v8s hl, v8s& oh, v8s& ol){
#pragma unroll
    for (int j=0;j<8;j++){
        float v = bf2f((unsigned short)hh[j]) + bf2f((unsigned short)hl[j]);
        float a = lrelu(v);
        unsigned short h = f2bf(a);
        oh[j] = (short)h;
        ol[j] = (short)f2bf(a - bf2f(h));
    }
}

// ---------------- fused packing helpers ----------------
__device__ __forceinline__ void pf_item(const float* W, int K, int KB, int i,
                                        unsigned short* out){
    int l = i & 63, fb = i >> 6;
    int kb = fb % KB, nt = fb / KB;
    int n = nt*16 + (l&15);
    int k0 = kb*32 + ((l>>4)*8);
#pragma unroll
    for (int j=0;j<8;j++) out[i*8+j] = f2bf(W[(size_t)n*K + k0 + j]);
}
__device__ __forceinline__ void phl_item(const float* W, int K, int KB, int i,
                                         unsigned short* hi, unsigned short* lo){
    int l = i & 63, fb = i >> 6;
    int kb = fb % KB, nt = fb / KB;
    int n = nt*16 + (l&15);
    int k0 = kb*32 + ((l>>4)*8);
#pragma unroll
    for (int j=0;j<8;j++){
        float v = W[(size_t)n*K + k0 + j];
        unsigned short h = f2bf(v);
        hi[i*8+j] = h;
        lo[i*8+j] = f2bf(v - bf2f(h));
    }
}
__device__ __forceinline__ void pcat_item(const float* Wa, const float* Wb,
                                          int K1, int K, int KB, int i,
                                          unsigned short* out){
    int l = i & 63, fb = i >> 6;
    int kb = fb % KB, nt = fb / KB;
    int n = nt*16 + (l&15);
    int k0 = kb*32 + ((l>>4)*8);
#pragma unroll
    for (int j=0;j<8;j++){
        int k = k0 + j;
        float v = (k < K1) ? Wa[(size_t)n*K1 + k] : Wb[(size_t)n*(K-K1) + (k-K1)];
        out[i*8+j] = f2bf(v);
    }
}
__device__ __forceinline__ void pproj_item(const float* Wf, const float* Ws, int i,
                                           unsigned short* hi, unsigned short* lo){
    int l = i & 63, fb = i >> 6;
    int kb = fb & 1, nt = fb >> 1;
    int n = nt*16 + (l&15);
    int d = n >> 6, c = n & 63;
    const float* W = (d < 2) ? Wf : Ws;
    int k0 = (d&1)*64 + kb*32 + ((l>>4)*8);
#pragma unroll
    for (int j=0;j<8;j++){
        float v = W[c*130 + k0 + j];
        unsigned short h = f2bf(v);
        hi[i*8+j] = h;
        lo[i*8+j] = f2bf(v - bf2f(h));
    }
}

// ---------------- all weight prep in ONE dispatch ----------------
__global__ void pack_all(
    const float* __restrict__ gWih, const float* __restrict__ gWhh,
    const float* __restrict__ Wdyn,
    const float* __restrict__ l0Whh, const float* __restrict__ l1Wih,
    const float* __restrict__ l1Whh, const float* __restrict__ l0Wih,
    const float* __restrict__ c1Wf, const float* __restrict__ c1Ws,
    const float* __restrict__ c2Wf, const float* __restrict__ c2Ws,
    unsigned short* __restrict__ pWih, unsigned short* __restrict__ pWhh,
    unsigned short* __restrict__ pWdyn,
    unsigned short* __restrict__ B0h, unsigned short* __restrict__ B1h,
    unsigned short* __restrict__ P1h, unsigned short* __restrict__ P1l,
    unsigned short* __restrict__ P2h, unsigned short* __restrict__ P2l,
    unsigned short* __restrict__ GIh, unsigned short* __restrict__ GIl,
    int* __restrict__ cnt, int* __restrict__ gtot)
{
    int i = blockIdx.x*256 + threadIdx.x;
    if (i < 768){ pf_item(gWih, 32, 1, i, pWih); return; }   i -= 768;
    if (i < 1536){ pf_item(gWhh, 64, 2, i, pWhh); return; }  i -= 1536;
    if (i < 512){ pf_item(Wdyn, 64, 2, i, pWdyn); return; }  i -= 512;
    if (i < 8192){ pcat_item(l0Whh, l0Whh, 128, 128, 4, i, B0h); return; } i -= 8192;
    if (i < 16384){ pcat_item(l1Wih, l1Whh, 128, 256, 8, i, B1h); return; } i -= 16384;
    if (i < 2048){ pproj_item(c1Wf, c1Ws, i, P1h, P1l); return; } i -= 2048;
    if (i < 2048){ pproj_item(c2Wf, c2Ws, i, P2h, P2l); return; } i -= 2048;
    if (i < 8192){ phl_item(l0Wih, 128, 4, i, GIh, GIl); return; } i -= 8192;
    if (i < NN){ cnt[i] = 0; return; } i -= NN;
    if (i < 1){ gtot[0] = 0; return; }
}
#define PACK_TOTAL (768+1536+512+8192+16384+2048+2048+8192+NN+1)

// ---------------- GRU encoder v13: + fused edge-count histogram ----------------
// R25: the count kernel's ~15us of random atomics sat serially in the stream.
// The encoder runs at 35% occupancy (latency-bound, spare issue slots), so
// blocks >= NN/16 of THIS dispatch do the histogram in its shadow. Per-BLOCK
// branch: count blocks never reach a barrier (whole block returns), encoder
// blocks unchanged. count completes before alloc (next dispatch). Encoder
// body = v12 (R9), byte-identical.
#define ENCB (NN/16)
#define CNTB ((EE+255)/256)
__global__ __launch_bounds__(256) void encoder_mfma(
    const float* __restrict__ x,
    const float* __restrict__ Wip, const float* __restrict__ bip,
    const unsigned short* __restrict__ pWih,
    const unsigned short* __restrict__ pWhh,
    const float* __restrict__ bih, const float* __restrict__ bhh,
    const unsigned short* __restrict__ pWdyn,
    const float* __restrict__ bdyn,
    float* __restrict__ hist,
    const int* __restrict__ ei, int* __restrict__ cnt)
{
    __shared__ unsigned short efh[4*512], efl[4*512];          // e A-frags, 4-step window
    __shared__ unsigned short hfh[2][1024], hfl[2][1024];      // dbuf h A-frags (swizzled)
    const int tid = threadIdx.x;

    if (blockIdx.x >= ENCB){
        int e = (blockIdx.x - ENCB)*256 + tid;
        if (e < EE) atomicAdd(&cnt[ei[EE+e]], 1);
        return;
    }

    const int l   = tid & 63;
    const int w   = tid >> 6;          // wave owns g-tile w
    const int ln  = l & 15, q = l >> 4;
    const int blk = blockIdx.x;
    const int rsw = ((l>>1)&7)<<3;     // read swizzle key

    for (int i = tid; i < 1024; i += 256){
        hfh[0][i]=0; hfl[0][i]=0; hfh[1][i]=0; hfl[1][i]=0;
    }

    // e-compute decomposition: thread owns ONE k (3 weight regs) + 2 nodes
    const int k0 = tid & 31;
    const int mb = tid >> 5;           // nodes 2mb, 2mb+1
    const float ew0 = Wip[2*k0], ew1 = Wip[2*k0+1], ebk = bip[k0];
    const int ebase = (k0>>3)*128 + (k0&7);
    const float2* xr0 = (const float2*)(x + (size_t)(blk*16 + 2*mb    )*32);
    const float2* xr1 = (const float2*)(x + (size_t)(blk*16 + 2*mb + 1)*32);

    const int c = w*16 + ln;
    const float bR  = bih[c]       + bhh[c];
    const float bZ  = bih[64 + c]  + bhh[64 + c];
    const float bNI = bih[128 + c];
    const float bNH = bhh[128 + c];
    float hprev[4] = {0.f,0.f,0.f,0.f};

    const v8s* FIH = (const v8s*)pWih;
    const v8s* FHH = (const v8s*)pWhh;
    const v8s* FDY = (const v8s*)pWdyn;
    const int wbase = (c>>5)*512 + (16*((c&31)>>3))*8 + (c&7);
    __syncthreads();                   // h zero-init ready

    int p = 0;
#pragma unroll 1
    for (int tb = 0; tb < 4; tb++){
#pragma unroll
        for (int ts = 0; ts < 4; ts++){
            int t = tb*4 + ts;
            float2 xv0 = xr0[t], xv1 = xr1[t];
            float e0 = lrelu(ew0*xv0.x + ew1*xv0.y + ebk);
            float e1 = lrelu(ew0*xv1.x + ew1*xv1.y + ebk);
            unsigned short h_, l_;
            tsplit(e0, h_, l_);
            efh[ts*512 + ebase + (2*mb  )*8] = h_;
            efl[ts*512 + ebase + (2*mb  )*8] = l_;
            tsplit(e1, h_, l_);
            efh[ts*512 + ebase + (2*mb+1)*8] = h_;
            efl[ts*512 + ebase + (2*mb+1)*8] = l_;
        }
        __syncthreads();               // ef window ready
#pragma unroll 1
        for (int ts = 0; ts < 4; ts++){
            v8s eh  = *(const v8s*)&efh[ts*512 + l*8];
            v8s el  = *(const v8s*)&efl[ts*512 + l*8];
            v8s h0h = *(const v8s*)&hfh[p][(l*8) ^ rsw];
            v8s h0l = *(const v8s*)&hfl[p][(l*8) ^ rsw];
            v8s h1h = *(const v8s*)&hfh[p][512 + ((l*8) ^ rsw)];
            v8s h1l = *(const v8s*)&hfl[p][512 + ((l*8) ^ rsw)];

            v4f aR = {bR,bR,bR,bR};
            v4f aZ = {bZ,bZ,bZ,bZ};
            v4f aNI= {bNI,bNI,bNI,bNI};
            v4f aNH= {bNH,bNH,bNH,bNH};
            v8s b;
            b = FIH[(w   )*64 + l];    aR = MFMA16(eh,b,aR);  aR = MFMA16(el,b,aR);
            b = FHH[(w*2+0)*64+l];     aR = MFMA16(h0h,b,aR); aR = MFMA16(h0l,b,aR);
            b = FHH[(w*2+1)*64+l];     aR = MFMA16(h1h,b,aR); aR = MFMA16(h1l,b,aR);
            b = FIH[(4+w )*64 + l];    aZ = MFMA16(eh,b,aZ);  aZ = MFMA16(el,b,aZ);
            b = FHH[((4+w)*2+0)*64+l]; aZ = MFMA16(h0h,b,aZ); aZ = MFMA16(h0l,b,aZ);
            b = FHH[((4+w)*2+1)*64+l]; aZ = MFMA16(h1h,b,aZ); aZ = MFMA16(h1l,b,aZ);
            b = FIH[(8+w )*64 + l];    aNI= MFMA16(eh,b,aNI); aNI= MFMA16(el,b,aNI);
            b = FHH[((8+w)*2+0)*64+l]; aNH= MFMA16(h0h,b,aNH);aNH= MFMA16(h0l,b,aNH);
            b = FHH[((8+w)*2+1)*64+l]; aNH= MFMA16(h1h,b,aNH);aNH= MFMA16(h1l,b,aNH);

#pragma unroll
            for (int i = 0; i < 4; i++){
                float r_ = fsig(aR[i]);
                float z_ = fsig(aZ[i]);
                float nn_ = ftanh(aNI[i] + r_*aNH[i]);
                float hn = nn_ + z_*(hprev[i] - nn_);
                hprev[i] = hn;
                int row = q*4 + i;
                int off = (wbase + row*8) ^ ((((row)>>1)&7)<<3);
                unsigned short hh_, hl_;
                tsplit(hn, hh_, hl_);
                hfh[1-p][off] = hh_;
                hfl[1-p][off] = hl_;
            }
            __syncthreads();   // per-step barrier
            p ^= 1;
        }
    }
    {
        v8s a0h,a0l,a1h,a1l;
        lrelu_resplit(*(const v8s*)&hfh[p][(l*8) ^ rsw],
                      *(const v8s*)&hfl[p][(l*8) ^ rsw],       a0h, a0l);
        lrelu_resplit(*(const v8s*)&hfh[p][512 + ((l*8) ^ rsw)],
                      *(const v8s*)&hfl[p][512 + ((l*8) ^ rsw)], a1h, a1l);
        const int nt = w;
        float bb = bdyn[nt*16 + ln];
        v4f acc = {bb,bb,bb,bb};
        v8s b;
        b = FDY[(nt*2+0)*64 + l]; acc = MFMA16(a0h,b,acc); acc = MFMA16(a0l,b,acc);
        b = FDY[(nt*2+1)*64 + l]; acc = MFMA16(a1h,b,acc); acc = MFMA16(a1l,b,acc);
#pragma unroll
        for (int i = 0; i < 4; i++){
            hist[(size_t)(blk*16 + q*4 + i)*64 + nt*16 + ln] = lrelu(acc[i]);
        }
    }
}

// ---------------- CGConv projections v2: f16-packed B-gates (unchanged) ----------------
#define PROJ_ACC(NT, ACC) { \
    v8s bh0_ = FH[((NT)*2+0)*64 + l], bl0_ = FL[((NT)*2+0)*64 + l]; \
    v8s bh1_ = FH[((NT)*2+1)*64 + l], bl1_ = FL[((NT)*2+1)*64 + l]; \
    ACC = MFMA16(ah0,bh0_,ACC); ACC = MFMA16(al0,bh0_,ACC); ACC = MFMA16(ah0,bl0_,ACC); \
    ACC = MFMA16(ah1,bh1_,ACC); ACC = MFMA16(al1,bh1_,ACC); ACC = MFMA16(ah1,bl1_,ACC); }

__global__ __launch_bounds__(256) void proj_mfma(
    const float* __restrict__ xin,
    const unsigned short* __restrict__ Bh, const unsigned short* __restrict__ Bl,
    float* __restrict__ Af, float* __restrict__ As,
    unsigned* __restrict__ BP)
{
    __shared__ float sx[64*68];
    const int tid = threadIdx.x;
    const int l = tid & 63;
    const int w = tid >> 6;
    const int ln = l & 15, q = l >> 4;
    const int n0 = blockIdx.x*64;

    for (int i=tid;i<64*16;i+=256){
        int nn = i>>4, f4 = i&15;
        float4 v = {0.f,0.f,0.f,0.f};
        if (n0+nn < NN) v = ((const float4*)(xin + (size_t)(n0+nn)*64))[f4];
        *(float4*)&sx[nn*68 + f4*4] = v;
    }
    __syncthreads();

    v8s ah0,al0,ah1,al1;
    cvt8(&sx[(w*16+ln)*68 +      q*8], ah0, al0);
    cvt8(&sx[(w*16+ln)*68 + 32 + q*8], ah1, al1);

    const v8s* FH = (const v8s*)Bh;
    const v8s* FL = (const v8s*)Bl;
#pragma unroll 1
    for (int c3=0; c3<4; c3++){
        v4f aA = {0.f,0.f,0.f,0.f};
        v4f aS = aA, aF = aA, aB = aA;
        PROJ_ACC(c3,      aA);
        PROJ_ACC(8 + c3,  aS);
        PROJ_ACC(4 + c3,  aF);
        PROJ_ACC(12 + c3, aB);
        int col = c3*16 + ln;
#pragma unroll
        for (int i=0;i<4;i++){
            int node = n0 + w*16 + q*4 + i;
            if (node < NN){
                Af[(size_t)node*64 + col] = aA[i];
                As[(size_t)node*64 + col] = aS[i];
                unsigned pf = __half_as_ushort(__float2half(aF[i]));
                unsigned ps = __half_as_ushort(__float2half(aB[i]));
                BP[(size_t)node*64 + col] = pf | (ps << 16);
            }
        }
    }
}

// ---------------- dst segment build: alloc + scatter ----------------
__global__ void alloc_kernel(const int* __restrict__ cnt, int* __restrict__ gtot,
                             int* __restrict__ off, int* __restrict__ cur){
    int n = blockIdx.x*256 + threadIdx.x;
    if (n >= NN) return;
    int c = cnt[n];
    int s = atomicAdd(gtot, c);
    off[n] = s;
    cur[n] = s;
}

// scatter: 8-byte records {src:int, ea:2xf16}
__global__ void scatter_kernel(const int* __restrict__ ei, const float* __restrict__ ea,
                               int* __restrict__ cur, int2* __restrict__ recS){
    int e = blockIdx.x*256 + threadIdx.x;
    if (e >= EE) return;
    int d = ei[EE+e];
    int p = atomicAdd(&cur[d], 1);
    unsigned e0 = __half_as_ushort(__float2half(ea[2*(size_t)e]));
    unsigned e1 = __half_as_ushort(__float2half(ea[2*(size_t)e+1]));
    int2 r;
    r.x = ei[e];
    r.y = (int)(e0 | (e1 << 16));
    recS[p] = r;
}

// ---------------- CGConv aggregate: 4-edge unroll for gather MLP ----------------
// R25: one wave/node with 2 edges in flight is latency-bound on the random
// BP gathers (~700cy L2-miss each; 12.8MB working set >> 4MB per-XCD L2).
// 4-edge unroll doubles gathers in flight; tail via 1-edge loop.
__device__ __forceinline__ float edge_term(
    int2 r, const unsigned* BPc,
    float afd, float asd, float wf0, float wf1, float ws0, float ws1)
{
    unsigned ea = (unsigned)r.y;
    float e0 = __half2float(__ushort_as_half((unsigned short)(ea & 0xFFFFu)));
    float e1 = __half2float(__ushort_as_half((unsigned short)(ea >> 16)));
    unsigned pv = BPc[(size_t)r.x*64];
    float bfv = __half2float(__ushort_as_half((unsigned short)(pv & 0xFFFFu)));
    float bsv = __half2float(__ushort_as_half((unsigned short)(pv >> 16)));
    float gf = afd + bfv + wf0*e0 + wf1*e1;
    float gs = asd + bsv + ws0*e0 + ws1*e1;
    return fsig(gf)*fsoftplus(gs);
}

__global__ __launch_bounds__(256) void cg_agg(
    const float* __restrict__ xin,
    const int2* __restrict__ recS,
    const int* __restrict__ off, const int* __restrict__ cnt,
    const float* __restrict__ Wf, const float* __restrict__ bf,
    const float* __restrict__ Ws, const float* __restrict__ bs,
    const float* __restrict__ Af, const float* __restrict__ As,
    const unsigned* __restrict__ BP,
    const float* __restrict__ gamma, const float* __restrict__ beta,
    const float* __restrict__ mean, const float* __restrict__ var,
    float* __restrict__ outp)
{
    const int tid = threadIdx.x;
    const int c = tid & 63, wid = tid >> 6;
    const int n = blockIdx.x*4 + wid;
    if (n >= NN) return;

    const float wf0 = Wf[c*130+128], wf1 = Wf[c*130+129], bfc = bf[c];
    const float ws0 = Ws[c*130+128], ws1 = Ws[c*130+129], bsc = bs[c];
    const float afd = Af[(size_t)n*64+c] + bfc, asd = As[(size_t)n*64+c] + bsc;
    const unsigned* BPc = BP + c;

    float acc = 0.f;
    int i = off[n];
    const int i1 = i + cnt[n];
#pragma unroll 1
    for (; i+3 < i1; i += 4){
        int2 r0 = recS[i], r1 = recS[i+1], r2 = recS[i+2], r3 = recS[i+3];
        // 4 independent gathers issue before any use
        acc += edge_term(r0, BPc, afd, asd, wf0, wf1, ws0, ws1);
        acc += edge_term(r1, BPc, afd, asd, wf0, wf1, ws0, ws1);
        acc += edge_term(r2, BPc, afd, asd, wf0, wf1, ws0, ws1);
        acc += edge_term(r3, BPc, afd, asd, wf0, wf1, ws0, ws1);
    }
#pragma unroll 1
    for (; i < i1; i++){
        acc += edge_term(recS[i], BPc, afd, asd, wf0, wf1, ws0, ws1);
    }
    float bn = (acc - mean[c])*rsqrtf(var[c]+BN_EPS)*gamma[c] + beta[c];
    outp[(size_t)n*64+c] = xin[(size_t)n*64+c] + bn;
}

// ---------------- target gather + nbrs linear + concat (unchanged) ----------------
__global__ __launch_bounds__(256) void target_kernel(
    const float* __restrict__ hist, const float* __restrict__ f2,
    const int* __restrict__ tgt,
    const float* __restrict__ Wn, const float* __restrict__ bn_,
    float* __restrict__ enc)
{
    const int tid=threadIdx.x;
    const int c = tid&63, q = tid>>6;
    const int b = blockIdx.x*4 + q;
    if (b>=BB) return;
    const int n = tgt[b];
    float a = bn_[c];
#pragma unroll
    for (int k=0;k<ENC;k++) a += Wn[c*64+k]*f2[(size_t)n*64+k];
    enc[(size_t)b*128 + 64 + c] = lrelu(a);
    enc[(size_t)b*128 + c]      = hist[(size_t)n*64+c];
}

// ---------------- gi0 via MFMA (unchanged) ----------------
__global__ __launch_bounds__(512) void gi0_mfma(
    const float* __restrict__ enc,
    const unsigned short* __restrict__ GIh, const unsigned short* __restrict__ GIl,
    const float* __restrict__ bih0, const float* __restrict__ bhh0,
    float* __restrict__ gi0)
{
    __shared__ float senc[16*132];
    const int tid = threadIdx.x;
    const int l = tid & 63;
    const int w = tid >> 6;
    const int ln = l & 15, q = l >> 4;
    const int b0 = blockIdx.x*16;

    for (int i=tid;i<16*32;i+=512){
        int row = i>>5, f4 = i&31;
        *(float4*)&senc[row*132 + f4*4] = ((const float4*)(enc + (size_t)(b0+row)*128))[f4];
    }
    __syncthreads();

    v8s ah[4], al[4];
#pragma unroll
    for (int kb=0;kb<4;kb++) cvt8(&senc[ln*132 + kb*32 + q*8], ah[kb], al[kb]);

    const v8s* FH = (const v8s*)GIh;
    const v8s* FL = (const v8s*)GIl;
#pragma unroll
    for (int u=0;u<4;u++){
        int nt = w*4 + u;
        int col = nt*16 + ln;
        float bb = bih0[col] + bhh0[col];
        v4f acc = {bb,bb,bb,bb};
#pragma unroll
        for (int kb=0;kb<4;kb++){
            v8s bh = FH[(nt*4+kb)*64 + l];
            v8s bl = FL[(nt*4+kb)*64 + l];
            acc = MFMA16(ah[kb],bh,acc); acc = MFMA16(al[kb],bh,acc); acc = MFMA16(ah[kb],bl,acc);
        }
#pragma unroll
        for (int i=0;i<4;i++)
            gi0[(size_t)(b0 + q*4 + i)*512 + col] = acc[i];
    }
}

// ---------------- 2-layer LSTM decoder (sW0 in LDS, W1r in regs; unchanged) ----------------
#define LMB 16
__global__ __launch_bounds__(512)
__attribute__((amdgpu_waves_per_eu(2,2)))
void lstm_mfma(
    const float* __restrict__ gi0,
    const unsigned short* __restrict__ B0h,
    const unsigned short* __restrict__ B1h,
    const float* __restrict__ bih1, const float* __restrict__ bhh1,
    float* __restrict__ h1buf)
{
    __shared__ int4 sW0[32*4*64];                                // 131072 B
    __shared__ unsigned short h0hi[2][4*512], h0lo[2][4*512];    // 16384 B
    __shared__ unsigned short h1hi[2][4*512], h1lo[2][4*512];    // 16384 B
    const int tid = threadIdx.x;
    const int l = tid & 63;
    const int w = tid >> 6;
    const int c = l & 15;
    const int q = l >> 4;
    const int j = w*16 + c;
    const int b0 = blockIdx.x*LMB;
    const int lsw = ((l>>1)&7)<<3;     // read swizzle key (row = l)

    {
        const int4* F0 = (const int4*)B0h;
        for (int i=tid;i<32*4*64;i+=512) sW0[i] = F0[i];
    }
    for (int i=tid;i<4*512;i+=512){
        h0hi[0][i]=0; h0lo[0][i]=0; h0hi[1][i]=0; h0lo[1][i]=0;
        h1hi[0][i]=0; h1lo[0][i]=0; h1hi[1][i]=0; h1lo[1][i]=0;
    }

    int4 W1r[32];
    {
        const int4* F1 = (const int4*)B1h;
#pragma unroll
        for (int g=0;g<4;g++)
#pragma unroll
            for (int kb=0;kb<8;kb++) W1r[g*8+kb] = F1[((g*8+w)*8 + kb)*64 + l];
#pragma unroll
        for (int i=0;i<32;i++)
            asm volatile("" : "+v"(W1r[i].x), "+v"(W1r[i].y), "+v"(W1r[i].z), "+v"(W1r[i].w));
    }

    float rgi[4][4];
#pragma unroll
    for (int g=0;g<4;g++)
#pragma unroll
        for (int i=0;i<4;i++)
            rgi[g][i] = gi0[(size_t)(b0 + q*4 + i)*512 + g*128 + j];

    float b1[4];
#pragma unroll
    for (int g=0;g<4;g++) b1[g] = bih1[g*128+j] + bhh1[g*128+j];
    float c0[4] = {0,0,0,0}, c1[4] = {0,0,0,0};
    const int kbw = j>>5, qw = (j>>3)&3, jw = j&7;
    __syncthreads();

    int p = 0;
#pragma unroll 1
    for (int t=0;t<OUTL;t++){
        // ---- layer 0: read h0[p], write h0[1-p]; dual hi/lo accumulators ----
        v4f aH[4], aL[4];
#pragma unroll
        for (int g=0;g<4;g++){
            v4f t4 = {rgi[g][0], rgi[g][1], rgi[g][2], rgi[g][3]};
            aH[g] = t4;
            v4f z = {0.f,0.f,0.f,0.f};
            aL[g] = z;
        }
#pragma unroll
        for (int kb=0;kb<4;kb++){
            v8s ah = *(const v8s*)&h0hi[p][kb*512 + ((l*8) ^ lsw)];
            v8s al = *(const v8s*)&h0lo[p][kb*512 + ((l*8) ^ lsw)];
#pragma unroll
            for (int g=0;g<4;g++){
                v8s bfr = as_v8s(sW0[((g*8+w)*4 + kb)*64 + l]);
                aH[g] = MFMA16(ah, bfr, aH[g]);
                aL[g] = MFMA16(al, bfr, aL[g]);
            }
        }
#pragma unroll
        for (int i=0;i<4;i++){
            float gi_ = aH[0][i]+aL[0][i], gf_ = aH[1][i]+aL[1][i];
            float gg_ = aH[2][i]+aL[2][i], go_ = aH[3][i]+aL[3][i];
            c0[i] = fsig(gf_)*c0[i] + fsig(gi_)*ftanh(gg_);
            float hn = fsig(go_)*ftanh(c0[i]);
            int row = q*4 + i;
            int off = (kbw*512 + (qw*16 + row)*8 + jw) ^ (((row>>1)&7)<<3);
            unsigned short h = f2bf(hn);
            h0hi[1-p][off] = h;
            h0lo[1-p][off] = f2bf(hn - bf2f(h));
        }
        __syncthreads();   // B1: the ONLY barrier per step

        // ---- layer 1: read h0[1-p] + h1[p], write h1[1-p] ----
        v4f bH[4], bL[4];
#pragma unroll
        for (int g=0;g<4;g++){
            v4f t4={b1[g],b1[g],b1[g],b1[g]}; bH[g]=t4;
            v4f z={0.f,0.f,0.f,0.f}; bL[g]=z;
        }
#pragma unroll
        for (int kb=0;kb<8;kb++){
            const unsigned short* hb = (kb<4) ? h0hi[1-p] : h1hi[p];
            const unsigned short* lb = (kb<4) ? h0lo[1-p] : h1lo[p];
            int kk = kb & 3;
            v8s ah = *(const v8s*)&hb[kk*512 + ((l*8) ^ lsw)];
            v8s al = *(const v8s*)&lb[kk*512 + ((l*8) ^ lsw)];
#pragma unroll
            for (int g=0;g<4;g++){
                bH[g] = MFMA16(ah, as_v8s(W1r[g*8+kb]), bH[g]);
                bL[g] = MFMA16(al, as_v8s(W1r[g*8+kb]), bL[g]);
            }
        }
        float h1new[4];
#pragma unroll
        for (int i=0;i<4;i++){
            float gi_ = bH[0][i]+bL[0][i], gf_ = bH[1][i]+bL[1][i];
            float gg_ = bH[2][i]+bL[2][i], go_ = bH[3][i]+bL[3][i];
            c1[i] = fsig(gf_)*c1[i] + fsig(gi_)*ftanh(gg_);
            h1new[i] = fsig(go_)*ftanh(c1[i]);
            int row = q*4 + i;
            int off = (kbw*512 + (qw*16 + row)*8 + jw) ^ (((row>>1)&7)<<3);
            unsigned short h = f2bf(h1new[i]);
            h1hi[1-p][off] = h;
            h1lo[1-p][off] = f2bf(h1new[i] - bf2f(h));
        }

        // ---- out-proj deferred: stream h1 (f32) to global scratch ----
#pragma unroll
        for (int i=0;i<4;i++){
            h1buf[((size_t)(b0 + q*4 + i)*OUTL + t)*DEC + j] = h1new[i];
        }
        p ^= 1;
    }
}

// ---------------- out-projection: fut = h1buf @ Wop^T + bop (unchanged) ----------------
__global__ __launch_bounds__(256) void out_proj(
    const float* __restrict__ h1buf,
    const float* __restrict__ Wop, const float* __restrict__ bop,
    float* __restrict__ outp)
{
    int idx = blockIdx.x*256 + threadIdx.x;      // idx = b*OUTL + t
    if (idx >= BB*OUTL) return;
    const float4* hp = (const float4*)(h1buf + (size_t)idx*DEC);
    const float4* w0 = (const float4*)Wop;
    const float4* w1 = (const float4*)(Wop + DEC);
    float a0 = 0.f, a1 = 0.f;
#pragma unroll
    for (int k=0;k<32;k++){
        float4 h = hp[k], x0 = w0[k], x1 = w1[k];
        a0 += h.x*x0.x + h.y*x0.y + h.z*x0.z + h.w*x0.w;
        a1 += h.x*x1.x + h.y*x1.y + h.z*x1.z + h.w*x1.w;
    }
    outp[(size_t)idx*2    ] = a0 + bop[0];
    outp[(size_t)idx*2 + 1] = a1 + bop[1];
}

extern "C" void kernel_launch(void* const* d_in, const int* in_sizes, int n_in,
                              void* d_out, int out_size, void* d_ws, size_t ws_size,
                              hipStream_t stream)
{
    const float* x    = (const float*)d_in[0];
    const int*   ei   = (const int*)d_in[1];
    const float* ea   = (const float*)d_in[2];
    const int*   tgt  = (const int*)d_in[3];
    const float* Wip  = (const float*)d_in[4];
    const float* bip  = (const float*)d_in[5];
    const float* gWih = (const float*)d_in[6];
    const float* gWhh = (const float*)d_in[7];
    const float* gbih = (const float*)d_in[8];
    const float* gbhh = (const float*)d_in[9];
    const float* Wdyn = (const float*)d_in[10];
    const float* bdyn = (const float*)d_in[11];
    const float* c1Wf=(const float*)d_in[12]; const float* c1bf=(const float*)d_in[13];
    const float* c1Ws=(const float*)d_in[14]; const float* c1bs=(const float*)d_in[15];
    const float* c1g =(const float*)d_in[16]; const float* c1b =(const float*)d_in[17];
    const float* c1m =(const float*)d_in[18]; const float* c1v =(const float*)d_in[19];
    const float* c2Wf=(const float*)d_in[20]; const float* c2bf=(const float*)d_in[21];
    const float* c2Ws=(const float*)d_in[22]; const float* c2bs=(const float*)d_in[23];
    const float* c2g =(const float*)d_in[24]; const float* c2b =(const float*)d_in[25];
    const float* c2m =(const float*)d_in[26]; const float* c2v =(const float*)d_in[27];
    const float* Wn  =(const float*)d_in[28]; const float* bn_ =(const float*)d_in[29];
    const float* l0Wih=(const float*)d_in[30]; const float* l0Whh=(const float*)d_in[31];
    const float* l0bih=(const float*)d_in[32]; const float* l0bhh=(const float*)d_in[33];
    const float* l1Wih=(const float*)d_in[34]; const float* l1Whh=(const float*)d_in[35];
    const float* l1bih=(const float*)d_in[36]; const float* l1bhh=(const float*)d_in[37];
    const float* Wop =(const float*)d_in[38]; const float* bop=(const float*)d_in[39];

    float* ws = (float*)d_ws;
    size_t o = 0;
    float* hist = ws + o; o += (size_t)NN*ENC;
    float* f1   = ws + o; o += (size_t)NN*ENC;
    float* f2   = ws + o; o += (size_t)NN*ENC;
    float* Af   = ws + o; o += (size_t)NN*ENC;
    float* Bfs  = ws + o; o += (size_t)NN*ENC;   // BP slot (u32 packed B-gates)
    float* As   = ws + o; o += (size_t)NN*ENC;
    float* enc  = ws + o; o += (size_t)BB*2*ENC;
    float* gi0  = ws + o; o += (size_t)BB*4*DEC;
    unsigned short* pWih  = (unsigned short*)(ws + o); o += (size_t)12*64*8/2;
    unsigned short* pWhh  = (unsigned short*)(ws + o); o += (size_t)24*64*8/2;
    unsigned short* pWdyn = (unsigned short*)(ws + o); o += (size_t)8*64*8/2;
    unsigned short* B0h = (unsigned short*)(ws + o); o += (size_t)32*4*64*8/2;
    unsigned short* B1h = (unsigned short*)(ws + o); o += (size_t)32*8*64*8/2;
    unsigned short* P1h = (unsigned short*)(ws + o); o += (size_t)2048*8/2;
    unsigned short* P1l = (unsigned short*)(ws + o); o += (size_t)2048*8/2;
    unsigned short* P2h = (unsigned short*)(ws + o); o += (size_t)2048*8/2;
    unsigned short* P2l = (unsigned short*)(ws + o); o += (size_t)2048*8/2;
    unsigned short* GIh = (unsigned short*)(ws + o); o += (size_t)8192*8/2;
    unsigned short* GIl = (unsigned short*)(ws + o); o += (size_t)8192*8/2;
    int* cnt    = (int*)(ws + o); o += NN;
    int* offv   = (int*)(ws + o); o += NN+1;
    int* curv   = (int*)(ws + o); o += NN;
    int* gtot   = (int*)(ws + o); o += 1;
    o = (o + 3) & ~(size_t)3;               // align for int2 records
    int2* recS  = (int2*)(ws + o); o += (size_t)2*EE;

    unsigned* BP = (unsigned*)Bfs;

    // h1buf (BB*OUTL*DEC = 6.4M floats) aliases Af..Bfs (2*NN*ENC = 6.4M
    // floats): both dead after cg_agg #2 (stream-ordered before lstm_mfma).
    float* h1buf = Af;

    // --- all weight prep + cnt/gtot zero in one dispatch ---
    pack_all<<<(PACK_TOTAL+255)/256, 256, 0, stream>>>(
        gWih, gWhh, Wdyn, l0Whh, l1Wih, l1Whh, l0Wih,
        c1Wf, c1Ws, c2Wf, c2Ws,
        pWih, pWhh, pWdyn, B0h, B1h, P1h, P1l, P2h, P2l, GIh, GIl, cnt, gtot);

    // --- history encoder + fused edge-count histogram ---
    encoder_mfma<<<ENCB + CNTB, 256, 0, stream>>>(
        x, Wip, bip, pWih, pWhh, gbih, gbhh, pWdyn, bdyn, hist, ei, cnt);

    // --- dst segment build (count done above) ---
    alloc_kernel<<<(NN+255)/256, 256, 0, stream>>>(cnt, gtot, offv, curv);
    scatter_kernel<<<(EE+255)/256, 256, 0, stream>>>(ei, ea, curv, recS);

    // --- CGConv 1 ---
    proj_mfma<<<(NN+63)/64, 256, 0, stream>>>(hist, P1h, P1l, Af, As, BP);
    cg_agg<<<(NN+3)/4, 256, 0, stream>>>(hist, recS, offv, cnt,
                                         c1Wf,c1bf,c1Ws,c1bs, Af, As, BP,
                                         c1g,c1b,c1m,c1v, f1);

    // --- CGConv 2 ---
    proj_mfma<<<(NN+63)/64, 256, 0, stream>>>(f1, P2h, P2l, Af, As, BP);
    cg_agg<<<(NN+3)/4, 256, 0, stream>>>(f1, recS, offv, cnt,
                                         c2Wf,c2bf,c2Ws,c2bs, Af, As, BP,
                                         c2g,c2b,c2m,c2v, f2);

    // --- target encoding ---
    target_kernel<<<(BB+3)/4, 256, 0, stream>>>(hist, f2, tgt, Wn, bn_, enc);

    // --- LSTM decoder prep (MFMA gi0) ---
    gi0_mfma<<<BB/16, 512, 0, stream>>>(enc, GIh, GIl, l0bih, l0bhh, gi0);

    // --- LSTM decoder (sW0 in LDS, W1r in regs) ---
    lstm_mfma<<<BB/LMB, 512, 0, stream>>>(gi0, B0h, B1h,
                                          l1bih, l1bhh, h1buf);

    // --- out-projection ---
    out_proj<<<(BB*OUTL+255)/256, 256, 0, stream>>>(h1buf, Wop, bop, (float*)d_out);
}

// Round 14
// 522.900 us; speedup vs baseline: 1.1690x; 1.0342x over previous
//
#include <hip/hip_runtime.h>
#include <hip/hip_fp16.h>
#include <math.h>

#define NN   50000
#define TT   16
#define EE   800000
#define BB   2000
#define EMBD 32
#define ENC  64
#define DEC  128
#define OUTL 25
#define BN_EPS 1e-5f

typedef short v8s __attribute__((ext_vector_type(8)));
typedef float v4f __attribute__((ext_vector_type(4)));
#define MFMA16(a,b,c) __builtin_amdgcn_mfma_f32_16x16x32_bf16((a),(b),(c),0,0,0)

__device__ __forceinline__ float lrelu(float v){ return v >= 0.f ? v : 0.1f*v; }
__device__ __forceinline__ float fsig(float v){ return __builtin_amdgcn_rcpf(1.f + __expf(-v)); }
__device__ __forceinline__ float ftanh(float v){ return 2.f*__builtin_amdgcn_rcpf(1.f + __expf(-2.f*v)) - 1.f; }
__device__ __forceinline__ float fsoftplus(float v){
    return v > 15.f ? v : __logf(1.f + __expf(v));
}

__device__ __forceinline__ unsigned short f2bf(float f){
    unsigned u = __float_as_uint(f);
    u = u + 0x7FFFu + ((u>>16)&1u);
    return (unsigned short)(u>>16);
}
__device__ __forceinline__ float bf2f(unsigned short s){ return __uint_as_float(((unsigned)s)<<16); }

// truncation-based hi/lo split (R12)
__device__ __forceinline__ void tsplit(float v, unsigned short& hi, unsigned short& lo){
    unsigned u = __float_as_uint(v);
    hi = (unsigned short)(u >> 16);
    float r = v - __uint_as_float(u & 0xFFFF0000u);
    lo = (unsigned short)(__float_as_uint(r) >> 16);
}

__device__ __forceinline__ v8s as_v8s(int4 v){
    union { int4 i; v8s s; } u; u.i = v; return u.s;
}

__device__ __forceinline__ void cvt8(const float* p, v8s& hi, v8s& lo){
    float4 a0 = *(const float4*)p;
    float4 a1 = *(const float4*)(p+4);
    float av[8] = {a0.x,a0.y,a0.z,a0.w,a1.x,a1.y,a1.z,a1.w};
#pragma unroll
    for (int j=0;j<8;j++){
        unsigned short h = f2bf(av[j]);
        hi[j] = (short)h;
        lo[j] = (short)f2bf(av[j] - bf2f(h));
    }
}
// reconstruct hi+lo, lrelu, re-split
__device__ __forceinline__ void lrelu_resplit(v8s hh, v8s hl, v8s& oh, v8s& ol){
#pragma unroll
    for (int j=0;j<8;j++){
        float v = bf2f((unsigned short)hh[j]) + bf2f((unsigned short)hl[j]);
        float a = lrelu(v);
        unsigned short h = f2bf(a);
        oh[j] = (short)h;
        ol[j] = (short)f2bf(a - bf2f(h));
    }
}

// ---------------- fused packing helpers ----------------
__device__ __forceinline__ void pf_item(const float* W, int K, int KB, int i,
                                        unsigned short* out){
    int l = i & 63, fb = i >> 6;
    int kb = fb % KB, nt = fb / KB;
    int n = nt*16 + (l&15);
    int k0 = kb*32 + ((l>>4)*8);
#pragma unroll
    for (int j=0;j<8;j++) out[i*8+j] = f2bf(W[(size_t)n*K + k0 + j]);
}
__device__ __forceinline__ void phl_item(const float* W, int K, int KB, int i,
                                         unsigned short* hi, unsigned short* lo){
    int l = i & 63, fb = i >> 6;
    int kb = fb % KB, nt = fb / KB;
    int n = nt*16 + (l&15);
    int k0 = kb*32 + ((l>>4)*8);
#pragma unroll
    for (int j=0;j<8;j++){
        float v = W[(size_t)n*K + k0 + j];
        unsigned short h = f2bf(v);
        hi[i*8+j] = h;
        lo[i*8+j] = f2bf(v - bf2f(h));
    }
}
__device__ __forceinline__ void pcat_item(const float* Wa, const float* Wb,
                                          int K1, int K, int KB, int i,
                                          unsigned short* out){
    int l = i & 63, fb = i >> 6;
    int kb = fb % KB, nt = fb / KB;
    int n = nt*16 + (l&15);
    int k0 = kb*32 + ((l>>4)*8);
#pragma unroll
    for (int j=0;j<8;j++){
        int k = k0 + j;
        float v = (k < K1) ? Wa[(size_t)n*K1 + k] : Wb[(size_t)n*(K-K1) + (k-K1)];
        out[i*8+j] = f2bf(v);
    }
}
__device__ __forceinline__ void pproj_item(const float* Wf, const float* Ws, int i,
                                           unsigned short* hi, unsigned short* lo){
    int l = i & 63, fb = i >> 6;
    int kb = fb & 1, nt = fb >> 1;
    int n = nt*16 + (l&15);
    int d = n >> 6, c = n & 63;
    const float* W = (d < 2) ? Wf : Ws;
    int k0 = (d&1)*64 + kb*32 + ((l>>4)*8);
#pragma unroll
    for (int j=0;j<8;j++){
        float v = W[c*130 + k0 + j];
        unsigned short h = f2bf(v);
        hi[i*8+j] = h;
        lo[i*8+j] = f2bf(v - bf2f(h));
    }
}

// ---------------- all weight prep in ONE dispatch ----------------
__global__ void pack_all(
    const float* __restrict__ gWih, const float* __restrict__ gWhh,
    const float* __restrict__ Wdyn,
    const float* __restrict__ l0Whh, const float* __restrict__ l1Wih,
    const float* __restrict__ l1Whh, const float* __restrict__ l0Wih,
    const float* __restrict__ c1Wf, const float* __restrict__ c1Ws,
    const float* __restrict__ c2Wf, const float* __restrict__ c2Ws,
    unsigned short* __restrict__ pWih, unsigned short* __restrict__ pWhh,
    unsigned short* __restrict__ pWdyn,
    unsigned short* __restrict__ B0h, unsigned short* __restrict__ B1h,
    unsigned short* __restrict__ P1h, unsigned short* __restrict__ P1l,
    unsigned short* __restrict__ P2h, unsigned short* __restrict__ P2l,
    unsigned short* __restrict__ GIh, unsigned short* __restrict__ GIl,
    int* __restrict__ cnt, int* __restrict__ gtot)
{
    int i = blockIdx.x*256 + threadIdx.x;
    if (i < 768){ pf_item(gWih, 32, 1, i, pWih); return; }   i -= 768;
    if (i < 1536){ pf_item(gWhh, 64, 2, i, pWhh); return; }  i -= 1536;
    if (i < 512){ pf_item(Wdyn, 64, 2, i, pWdyn); return; }  i -= 512;
    if (i < 8192){ pcat_item(l0Whh, l0Whh, 128, 128, 4, i, B0h); return; } i -= 8192;
    if (i < 16384){ pcat_item(l1Wih, l1Whh, 128, 256, 8, i, B1h); return; } i -= 16384;
    if (i < 2048){ pproj_item(c1Wf, c1Ws, i, P1h, P1l); return; } i -= 2048;
    if (i < 2048){ pproj_item(c2Wf, c2Ws, i, P2h, P2l); return; } i -= 2048;
    if (i < 8192){ phl_item(l0Wih, 128, 4, i, GIh, GIl); return; } i -= 8192;
    if (i < NN){ cnt[i] = 0; return; } i -= NN;
    if (i < 1){ gtot[0] = 0; return; }
}
#define PACK_TOTAL (768+1536+512+8192+16384+2048+2048+8192+NN+1)

// ---------------- GRU encoder v13: + fused edge-count histogram (unchanged) ----------------
#define ENCB (NN/16)
#define CNTB ((EE+255)/256)
__global__ __launch_bounds__(256) void encoder_mfma(
    const float* __restrict__ x,
    const float* __restrict__ Wip, const float* __restrict__ bip,
    const unsigned short* __restrict__ pWih,
    const unsigned short* __restrict__ pWhh,
    const float* __restrict__ bih, const float* __restrict__ bhh,
    const unsigned short* __restrict__ pWdyn,
    const float* __restrict__ bdyn,
    float* __restrict__ hist,
    const int* __restrict__ ei, int* __restrict__ cnt)
{
    __shared__ unsigned short efh[4*512], efl[4*512];          // e A-frags, 4-step window
    __shared__ unsigned short hfh[2][1024], hfl[2][1024];      // dbuf h A-frags (swizzled)
    const int tid = threadIdx.x;

    if (blockIdx.x >= ENCB){
        int e = (blockIdx.x - ENCB)*256 + tid;
        if (e < EE) atomicAdd(&cnt[ei[EE+e]], 1);
        return;
    }

    const int l   = tid & 63;
    const int w   = tid >> 6;          // wave owns g-tile w
    const int ln  = l & 15, q = l >> 4;
    const int blk = blockIdx.x;
    const int rsw = ((l>>1)&7)<<3;     // read swizzle key

    for (int i = tid; i < 1024; i += 256){
        hfh[0][i]=0; hfl[0][i]=0; hfh[1][i]=0; hfl[1][i]=0;
    }

    // e-compute decomposition: thread owns ONE k (3 weight regs) + 2 nodes
    const int k0 = tid & 31;
    const int mb = tid >> 5;           // nodes 2mb, 2mb+1
    const float ew0 = Wip[2*k0], ew1 = Wip[2*k0+1], ebk = bip[k0];
    const int ebase = (k0>>3)*128 + (k0&7);
    const float2* xr0 = (const float2*)(x + (size_t)(blk*16 + 2*mb    )*32);
    const float2* xr1 = (const float2*)(x + (size_t)(blk*16 + 2*mb + 1)*32);

    const int c = w*16 + ln;
    const float bR  = bih[c]       + bhh[c];
    const float bZ  = bih[64 + c]  + bhh[64 + c];
    const float bNI = bih[128 + c];
    const float bNH = bhh[128 + c];
    float hprev[4] = {0.f,0.f,0.f,0.f};

    const v8s* FIH = (const v8s*)pWih;
    const v8s* FHH = (const v8s*)pWhh;
    const v8s* FDY = (const v8s*)pWdyn;
    const int wbase = (c>>5)*512 + (16*((c&31)>>3))*8 + (c&7);
    __syncthreads();                   // h zero-init ready

    int p = 0;
#pragma unroll 1
    for (int tb = 0; tb < 4; tb++){
#pragma unroll
        for (int ts = 0; ts < 4; ts++){
            int t = tb*4 + ts;
            float2 xv0 = xr0[t], xv1 = xr1[t];
            float e0 = lrelu(ew0*xv0.x + ew1*xv0.y + ebk);
            float e1 = lrelu(ew0*xv1.x + ew1*xv1.y + ebk);
            unsigned short h_, l_;
            tsplit(e0, h_, l_);
            efh[ts*512 + ebase + (2*mb  )*8] = h_;
            efl[ts*512 + ebase + (2*mb  )*8] = l_;
            tsplit(e1, h_, l_);
            efh[ts*512 + ebase + (2*mb+1)*8] = h_;
            efl[ts*512 + ebase + (2*mb+1)*8] = l_;
        }
        __syncthreads();               // ef window ready
#pragma unroll 1
        for (int ts = 0; ts < 4; ts++){
            v8s eh  = *(const v8s*)&efh[ts*512 + l*8];
            v8s el  = *(const v8s*)&efl[ts*512 + l*8];
            v8s h0h = *(const v8s*)&hfh[p][(l*8) ^ rsw];
            v8s h0l = *(const v8s*)&hfl[p][(l*8) ^ rsw];
            v8s h1h = *(const v8s*)&hfh[p][512 + ((l*8) ^ rsw)];
            v8s h1l = *(const v8s*)&hfl[p][512 + ((l*8) ^ rsw)];

            v4f aR = {bR,bR,bR,bR};
            v4f aZ = {bZ,bZ,bZ,bZ};
            v4f aNI= {bNI,bNI,bNI,bNI};
            v4f aNH= {bNH,bNH,bNH,bNH};
            v8s b;
            b = FIH[(w   )*64 + l];    aR = MFMA16(eh,b,aR);  aR = MFMA16(el,b,aR);
            b = FHH[(w*2+0)*64+l];     aR = MFMA16(h0h,b,aR); aR = MFMA16(h0l,b,aR);
            b = FHH[(w*2+1)*64+l];     aR = MFMA16(h1h,b,aR); aR = MFMA16(h1l,b,aR);
            b = FIH[(4+w )*64 + l];    aZ = MFMA16(eh,b,aZ);  aZ = MFMA16(el,b,aZ);
            b = FHH[((4+w)*2+0)*64+l]; aZ = MFMA16(h0h,b,aZ); aZ = MFMA16(h0l,b,aZ);
            b = FHH[((4+w)*2+1)*64+l]; aZ = MFMA16(h1h,b,aZ); aZ = MFMA16(h1l,b,aZ);
            b = FIH[(8+w )*64 + l];    aNI= MFMA16(eh,b,aNI); aNI= MFMA16(el,b,aNI);
            b = FHH[((8+w)*2+0)*64+l]; aNH= MFMA16(h0h,b,aNH);aNH= MFMA16(h0l,b,aNH);
            b = FHH[((8+w)*2+1)*64+l]; aNH= MFMA16(h1h,b,aNH);aNH= MFMA16(h1l,b,aNH);

#pragma unroll
            for (int i = 0; i < 4; i++){
                float r_ = fsig(aR[i]);
                float z_ = fsig(aZ[i]);
                float nn_ = ftanh(aNI[i] + r_*aNH[i]);
                float hn = nn_ + z_*(hprev[i] - nn_);
                hprev[i] = hn;
                int row = q*4 + i;
                int off = (wbase + row*8) ^ ((((row)>>1)&7)<<3);
                unsigned short hh_, hl_;
                tsplit(hn, hh_, hl_);
                hfh[1-p][off] = hh_;
                hfl[1-p][off] = hl_;
            }
            __syncthreads();   // per-step barrier
            p ^= 1;
        }
    }
    {
        v8s a0h,a0l,a1h,a1l;
        lrelu_resplit(*(const v8s*)&hfh[p][(l*8) ^ rsw],
                      *(const v8s*)&hfl[p][(l*8) ^ rsw],       a0h, a0l);
        lrelu_resplit(*(const v8s*)&hfh[p][512 + ((l*8) ^ rsw)],
                      *(const v8s*)&hfl[p][512 + ((l*8) ^ rsw)], a1h, a1l);
        const int nt = w;
        float bb = bdyn[nt*16 + ln];
        v4f acc = {bb,bb,bb,bb};
        v8s b;
        b = FDY[(nt*2+0)*64 + l]; acc = MFMA16(a0h,b,acc); acc = MFMA16(a0l,b,acc);
        b = FDY[(nt*2+1)*64 + l]; acc = MFMA16(a1h,b,acc); acc = MFMA16(a1l,b,acc);
#pragma unroll
        for (int i = 0; i < 4; i++){
            hist[(size_t)(blk*16 + q*4 + i)*64 + nt*16 + ln] = lrelu(acc[i]);
        }
    }
}

// ---------------- CGConv projections v3: + fused scatter (R14) ----------------
// Same per-block-branch pattern as R13's count fusion: blocks >= PROJB do the
// edge scatter (random atomics + 8B writes) in the MFMA blocks' occupancy
// shadow. Only dispatch #1 carries the extra blocks; deps hold (alloc ran
// before; cg_agg#1 needs both proj outputs AND recS, produced here).
#define PROJB ((NN+63)/64)
#define SCTB  ((EE+255)/256)
#define PROJ_ACC(NT, ACC) { \
    v8s bh0_ = FH[((NT)*2+0)*64 + l], bl0_ = FL[((NT)*2+0)*64 + l]; \
    v8s bh1_ = FH[((NT)*2+1)*64 + l], bl1_ = FL[((NT)*2+1)*64 + l]; \
    ACC = MFMA16(ah0,bh0_,ACC); ACC = MFMA16(al0,bh0_,ACC); ACC = MFMA16(ah0,bl0_,ACC); \
    ACC = MFMA16(ah1,bh1_,ACC); ACC = MFMA16(al1,bh1_,ACC); ACC = MFMA16(ah1,bl1_,ACC); }

__global__ __launch_bounds__(256) void proj_mfma(
    const float* __restrict__ xin,
    const unsigned short* __restrict__ Bh, const unsigned short* __restrict__ Bl,
    float* __restrict__ Af, float* __restrict__ As,
    unsigned* __restrict__ BP,
    const int* __restrict__ ei, const float* __restrict__ ea,
    int* __restrict__ cur, int2* __restrict__ recS)
{
    __shared__ float sx[64*68];
    const int tid = threadIdx.x;

    if (blockIdx.x >= PROJB){
        int e = (blockIdx.x - PROJB)*256 + tid;
        if (e < EE){
            int d = ei[EE+e];
            int p = atomicAdd(&cur[d], 1);
            unsigned e0 = __half_as_ushort(__float2half(ea[2*(size_t)e]));
            unsigned e1 = __half_as_ushort(__float2half(ea[2*(size_t)e+1]));
            int2 r;
            r.x = ei[e];
            r.y = (int)(e0 | (e1 << 16));
            recS[p] = r;
        }
        return;
    }

    const int l = tid & 63;
    const int w = tid >> 6;
    const int ln = l & 15, q = l >> 4;
    const int n0 = blockIdx.x*64;

    for (int i=tid;i<64*16;i+=256){
        int nn = i>>4, f4 = i&15;
        float4 v = {0.f,0.f,0.f,0.f};
        if (n0+nn < NN) v = ((const float4*)(xin + (size_t)(n0+nn)*64))[f4];
        *(float4*)&sx[nn*68 + f4*4] = v;
    }
    __syncthreads();

    v8s ah0,al0,ah1,al1;
    cvt8(&sx[(w*16+ln)*68 +      q*8], ah0, al0);
    cvt8(&sx[(w*16+ln)*68 + 32 + q*8], ah1, al1);

    const v8s* FH = (const v8s*)Bh;
    const v8s* FL = (const v8s*)Bl;
#pragma unroll 1
    for (int c3=0; c3<4; c3++){
        v4f aA = {0.f,0.f,0.f,0.f};
        v4f aS = aA, aF = aA, aB = aA;
        PROJ_ACC(c3,      aA);
        PROJ_ACC(8 + c3,  aS);
        PROJ_ACC(4 + c3,  aF);
        PROJ_ACC(12 + c3, aB);
        int col = c3*16 + ln;
#pragma unroll
        for (int i=0;i<4;i++){
            int node = n0 + w*16 + q*4 + i;
            if (node < NN){
                Af[(size_t)node*64 + col] = aA[i];
                As[(size_t)node*64 + col] = aS[i];
                unsigned pf = __half_as_ushort(__float2half(aF[i]));
                unsigned ps = __half_as_ushort(__float2half(aB[i]));
                BP[(size_t)node*64 + col] = pf | (ps << 16);
            }
        }
    }
}

// ---------------- dst segment build: alloc ----------------
__global__ void alloc_kernel(const int* __restrict__ cnt, int* __restrict__ gtot,
                             int* __restrict__ off, int* __restrict__ cur){
    int n = blockIdx.x*256 + threadIdx.x;
    if (n >= NN) return;
    int c = cnt[n];
    int s = atomicAdd(gtot, c);
    off[n] = s;
    cur[n] = s;
}

// ---------------- CGConv aggregate: 4-edge unroll (unchanged) ----------------
__device__ __forceinline__ float edge_term(
    int2 r, const unsigned* BPc,
    float afd, float asd, float wf0, float wf1, float ws0, float ws1)
{
    unsigned ea = (unsigned)r.y;
    float e0 = __half2float(__ushort_as_half((unsigned short)(ea & 0xFFFFu)));
    float e1 = __half2float(__ushort_as_half((unsigned short)(ea >> 16)));
    unsigned pv = BPc[(size_t)r.x*64];
    float bfv = __half2float(__ushort_as_half((unsigned short)(pv & 0xFFFFu)));
    float bsv = __half2float(__ushort_as_half((unsigned short)(pv >> 16)));
    float gf = afd + bfv + wf0*e0 + wf1*e1;
    float gs = asd + bsv + ws0*e0 + ws1*e1;
    return fsig(gf)*fsoftplus(gs);
}

__global__ __launch_bounds__(256) void cg_agg(
    const float* __restrict__ xin,
    const int2* __restrict__ recS,
    const int* __restrict__ off, const int* __restrict__ cnt,
    const float* __restrict__ Wf, const float* __restrict__ bf,
    const float* __restrict__ Ws, const float* __restrict__ bs,
    const float* __restrict__ Af, const float* __restrict__ As,
    const unsigned* __restrict__ BP,
    const float* __restrict__ gamma, const float* __restrict__ beta,
    const float* __restrict__ mean, const float* __restrict__ var,
    float* __restrict__ outp)
{
    const int tid = threadIdx.x;
    const int c = tid & 63, wid = tid >> 6;
    const int n = blockIdx.x*4 + wid;
    if (n >= NN) return;

    const float wf0 = Wf[c*130+128], wf1 = Wf[c*130+129], bfc = bf[c];
    const float ws0 = Ws[c*130+128], ws1 = Ws[c*130+129], bsc = bs[c];
    const float afd = Af[(size_t)n*64+c] + bfc, asd = As[(size_t)n*64+c] + bsc;
    const unsigned* BPc = BP + c;

    float acc = 0.f;
    int i = off[n];
    const int i1 = i + cnt[n];
#pragma unroll 1
    for (; i+3 < i1; i += 4){
        int2 r0 = recS[i], r1 = recS[i+1], r2 = recS[i+2], r3 = recS[i+3];
        acc += edge_term(r0, BPc, afd, asd, wf0, wf1, ws0, ws1);
        acc += edge_term(r1, BPc, afd, asd, wf0, wf1, ws0, ws1);
        acc += edge_term(r2, BPc, afd, asd, wf0, wf1, ws0, ws1);
        acc += edge_term(r3, BPc, afd, asd, wf0, wf1, ws0, ws1);
    }
#pragma unroll 1
    for (; i < i1; i++){
        acc += edge_term(recS[i], BPc, afd, asd, wf0, wf1, ws0, ws1);
    }
    float bn = (acc - mean[c])*rsqrtf(var[c]+BN_EPS)*gamma[c] + beta[c];
    outp[(size_t)n*64+c] = xin[(size_t)n*64+c] + bn;
}

// ---------------- target gather + nbrs linear + concat (unchanged) ----------------
__global__ __launch_bounds__(256) void target_kernel(
    const float* __restrict__ hist, const float* __restrict__ f2,
    const int* __restrict__ tgt,
    const float* __restrict__ Wn, const float* __restrict__ bn_,
    float* __restrict__ enc)
{
    const int tid=threadIdx.x;
    const int c = tid&63, q = tid>>6;
    const int b = blockIdx.x*4 + q;
    if (b>=BB) return;
    const int n = tgt[b];
    float a = bn_[c];
#pragma unroll
    for (int k=0;k<ENC;k++) a += Wn[c*64+k]*f2[(size_t)n*64+k];
    enc[(size_t)b*128 + 64 + c] = lrelu(a);
    enc[(size_t)b*128 + c]      = hist[(size_t)n*64+c];
}

// ---------------- gi0 via MFMA (unchanged) ----------------
__global__ __launch_bounds__(512) void gi0_mfma(
    const float* __restrict__ enc,
    const unsigned short* __restrict__ GIh, const unsigned short* __restrict__ GIl,
    const float* __restrict__ bih0, const float* __restrict__ bhh0,
    float* __restrict__ gi0)
{
    __shared__ float senc[16*132];
    const int tid = threadIdx.x;
    const int l = tid & 63;
    const int w = tid >> 6;
    const int ln = l & 15, q = l >> 4;
    const int b0 = blockIdx.x*16;

    for (int i=tid;i<16*32;i+=512){
        int row = i>>5, f4 = i&31;
        *(float4*)&senc[row*132 + f4*4] = ((const float4*)(enc + (size_t)(b0+row)*128))[f4];
    }
    __syncthreads();

    v8s ah[4], al[4];
#pragma unroll
    for (int kb=0;kb<4;kb++) cvt8(&senc[ln*132 + kb*32 + q*8], ah[kb], al[kb]);

    const v8s* FH = (const v8s*)GIh;
    const v8s* FL = (const v8s*)GIl;
#pragma unroll
    for (int u=0;u<4;u++){
        int nt = w*4 + u;
        int col = nt*16 + ln;
        float bb = bih0[col] + bhh0[col];
        v4f acc = {bb,bb,bb,bb};
#pragma unroll
        for (int kb=0;kb<4;kb++){
            v8s bh = FH[(nt*4+kb)*64 + l];
            v8s bl = FL[(nt*4+kb)*64 + l];
            acc = MFMA16(ah[kb],bh,acc); acc = MFMA16(al[kb],bh,acc); acc = MFMA16(ah[kb],bl,acc);
        }
#pragma unroll
        for (int i=0;i<4;i++)
            gi0[(size_t)(b0 + q*4 + i)*512 + col] = acc[i];
    }
}

// ---------------- 2-layer LSTM decoder + fused out-projection epilogue ----------------
// R14: each block wrote its own 16x25 h1buf rows; after __syncthreads (block-
// scope memory fence) 400 of 512 threads each do one (b,t) row's two 128-dots
// and write d_out directly. Deletes the out_proj dispatch + launch gap.
#define LMB 16
__global__ __launch_bounds__(512)
__attribute__((amdgpu_waves_per_eu(2,2)))
void lstm_mfma(
    const float* __restrict__ gi0,
    const unsigned short* __restrict__ B0h,
    const unsigned short* __restrict__ B1h,
    const float* __restrict__ bih1, const float* __restrict__ bhh1,
    float* __restrict__ h1buf,
    const float* __restrict__ Wop, const float* __restrict__ bop,
    float* __restrict__ outp)
{
    __shared__ int4 sW0[32*4*64];                                // 131072 B
    __shared__ unsigned short h0hi[2][4*512], h0lo[2][4*512];    // 16384 B
    __shared__ unsigned short h1hi[2][4*512], h1lo[2][4*512];    // 16384 B
    const int tid = threadIdx.x;
    const int l = tid & 63;
    const int w = tid >> 6;
    const int c = l & 15;
    const int q = l >> 4;
    const int j = w*16 + c;
    const int b0 = blockIdx.x*LMB;
    const int lsw = ((l>>1)&7)<<3;     // read swizzle key (row = l)

    {
        const int4* F0 = (const int4*)B0h;
        for (int i=tid;i<32*4*64;i+=512) sW0[i] = F0[i];
    }
    for (int i=tid;i<4*512;i+=512){
        h0hi[0][i]=0; h0lo[0][i]=0; h0hi[1][i]=0; h0lo[1][i]=0;
        h1hi[0][i]=0; h1lo[0][i]=0; h1hi[1][i]=0; h1lo[1][i]=0;
    }

    int4 W1r[32];
    {
        const int4* F1 = (const int4*)B1h;
#pragma unroll
        for (int g=0;g<4;g++)
#pragma unroll
            for (int kb=0;kb<8;kb++) W1r[g*8+kb] = F1[((g*8+w)*8 + kb)*64 + l];
#pragma unroll
        for (int i=0;i<32;i++)
            asm volatile("" : "+v"(W1r[i].x), "+v"(W1r[i].y), "+v"(W1r[i].z), "+v"(W1r[i].w));
    }

    float rgi[4][4];
#pragma unroll
    for (int g=0;g<4;g++)
#pragma unroll
        for (int i=0;i<4;i++)
            rgi[g][i] = gi0[(size_t)(b0 + q*4 + i)*512 + g*128 + j];

    float b1[4];
#pragma unroll
    for (int g=0;g<4;g++) b1[g] = bih1[g*128+j] + bhh1[g*128+j];
    float c0[4] = {0,0,0,0}, c1[4] = {0,0,0,0};
    const int kbw = j>>5, qw = (j>>3)&3, jw = j&7;
    __syncthreads();

    int p = 0;
#pragma unroll 1
    for (int t=0;t<OUTL;t++){
        // ---- layer 0: read h0[p], write h0[1-p]; dual hi/lo accumulators ----
        v4f aH[4], aL[4];
#pragma unroll
        for (int g=0;g<4;g++){
            v4f t4 = {rgi[g][0], rgi[g][1], rgi[g][2], rgi[g][3]};
            aH[g] = t4;
            v4f z = {0.f,0.f,0.f,0.f};
            aL[g] = z;
        }
#pragma unroll
        for (int kb=0;kb<4;kb++){
            v8s ah = *(const v8s*)&h0hi[p][kb*512 + ((l*8) ^ lsw)];
            v8s al = *(const v8s*)&h0lo[p][kb*512 + ((l*8) ^ lsw)];
#pragma unroll
            for (int g=0;g<4;g++){
                v8s bfr = as_v8s(sW0[((g*8+w)*4 + kb)*64 + l]);
                aH[g] = MFMA16(ah, bfr, aH[g]);
                aL[g] = MFMA16(al, bfr, aL[g]);
            }
        }
#pragma unroll
        for (int i=0;i<4;i++){
            float gi_ = aH[0][i]+aL[0][i], gf_ = aH[1][i]+aL[1][i];
            float gg_ = aH[2][i]+aL[2][i], go_ = aH[3][i]+aL[3][i];
            c0[i] = fsig(gf_)*c0[i] + fsig(gi_)*ftanh(gg_);
            float hn = fsig(go_)*ftanh(c0[i]);
            int row = q*4 + i;
            int off = (kbw*512 + (qw*16 + row)*8 + jw) ^ (((row>>1)&7)<<3);
            unsigned short h = f2bf(hn);
            h0hi[1-p][off] = h;
            h0lo[1-p][off] = f2bf(hn - bf2f(h));
        }
        __syncthreads();   // B1: the ONLY barrier per step

        // ---- layer 1: read h0[1-p] + h1[p], write h1[1-p] ----
        v4f bH[4], bL[4];
#pragma unroll
        for (int g=0;g<4;g++){
            v4f t4={b1[g],b1[g],b1[g],b1[g]}; bH[g]=t4;
            v4f z={0.f,0.f,0.f,0.f}; bL[g]=z;
        }
#pragma unroll
        for (int kb=0;kb<8;kb++){
            const unsigned short* hb = (kb<4) ? h0hi[1-p] : h1hi[p];
            const unsigned short* lb = (kb<4) ? h0lo[1-p] : h1lo[p];
            int kk = kb & 3;
            v8s ah = *(const v8s*)&hb[kk*512 + ((l*8) ^ lsw)];
            v8s al = *(const v8s*)&lb[kk*512 + ((l*8) ^ lsw)];
#pragma unroll
            for (int g=0;g<4;g++){
                bH[g] = MFMA16(ah, as_v8s(W1r[g*8+kb]), bH[g]);
                bL[g] = MFMA16(al, as_v8s(W1r[g*8+kb]), bL[g]);
            }
        }
        float h1new[4];
#pragma unroll
        for (int i=0;i<4;i++){
            float gi_ = bH[0][i]+bL[0][i], gf_ = bH[1][i]+bL[1][i];
            float gg_ = bH[2][i]+bL[2][i], go_ = bH[3][i]+bL[3][i];
            c1[i] = fsig(gf_)*c1[i] + fsig(gi_)*ftanh(gg_);
            h1new[i] = fsig(go_)*ftanh(c1[i]);
            int row = q*4 + i;
            int off = (kbw*512 + (qw*16 + row)*8 + jw) ^ (((row>>1)&7)<<3);
            unsigned short h = f2bf(h1new[i]);
            h1hi[1-p][off] = h;
            h1lo[1-p][off] = f2bf(h1new[i] - bf2f(h));
        }

        // ---- out-proj deferred: stream h1 (f32) to global scratch ----
#pragma unroll
        for (int i=0;i<4;i++){
            h1buf[((size_t)(b0 + q*4 + i)*OUTL + t)*DEC + j] = h1new[i];
        }
        p ^= 1;
    }

    // ---- fused out-projection epilogue: this block's 16x25 rows ----
    __syncthreads();    // block-scope fence: h1buf writes visible
    {
        const float bo0 = bop[0], bo1 = bop[1];
        const float4* w0 = (const float4*)Wop;
        const float4* w1 = (const float4*)(Wop + DEC);
        for (int r = tid; r < LMB*OUTL; r += 512){
            int b = b0 + r/OUTL, t = r%OUTL;
            const float4* hp = (const float4*)(h1buf + ((size_t)b*OUTL + t)*DEC);
            float a0 = 0.f, a1 = 0.f;
#pragma unroll
            for (int k=0;k<32;k++){
                float4 h = hp[k], x0 = w0[k], x1 = w1[k];
                a0 += h.x*x0.x + h.y*x0.y + h.z*x0.z + h.w*x0.w;
                a1 += h.x*x1.x + h.y*x1.y + h.z*x1.z + h.w*x1.w;
            }
            outp[((size_t)b*OUTL + t)*2    ] = a0 + bo0;
            outp[((size_t)b*OUTL + t)*2 + 1] = a1 + bo1;
        }
    }
}

extern "C" void kernel_launch(void* const* d_in, const int* in_sizes, int n_in,
                              void* d_out, int out_size, void* d_ws, size_t ws_size,
                              hipStream_t stream)
{
    const float* x    = (const float*)d_in[0];
    const int*   ei   = (const int*)d_in[1];
    const float* ea   = (const float*)d_in[2];
    const int*   tgt  = (const int*)d_in[3];
    const float* Wip  = (const float*)d_in[4];
    const float* bip  = (const float*)d_in[5];
    const float* gWih = (const float*)d_in[6];
    const float* gWhh = (const float*)d_in[7];
    const float* gbih = (const float*)d_in[8];
    const float* gbhh = (const float*)d_in[9];
    const float* Wdyn = (const float*)d_in[10];
    const float* bdyn = (const float*)d_in[11];
    const float* c1Wf=(const float*)d_in[12]; const float* c1bf=(const float*)d_in[13];
    const float* c1Ws=(const float*)d_in[14]; const float* c1bs=(const float*)d_in[15];
    const float* c1g =(const float*)d_in[16]; const float* c1b =(const float*)d_in[17];
    const float* c1m =(const float*)d_in[18]; const float* c1v =(const float*)d_in[19];
    const float* c2Wf=(const float*)d_in[20]; const float* c2bf=(const float*)d_in[21];
    const float* c2Ws=(const float*)d_in[22]; const float* c2bs=(const float*)d_in[23];
    const float* c2g =(const float*)d_in[24]; const float* c2b =(const float*)d_in[25];
    const float* c2m =(const float*)d_in[26]; const float* c2v =(const float*)d_in[27];
    const float* Wn  =(const float*)d_in[28]; const float* bn_ =(const float*)d_in[29];
    const float* l0Wih=(const float*)d_in[30]; const float* l0Whh=(const float*)d_in[31];
    const float* l0bih=(const float*)d_in[32]; const float* l0bhh=(const float*)d_in[33];
    const float* l1Wih=(const float*)d_in[34]; const float* l1Whh=(const float*)d_in[35];
    const float* l1bih=(const float*)d_in[36]; const float* l1bhh=(const float*)d_in[37];
    const float* Wop =(const float*)d_in[38]; const float* bop=(const float*)d_in[39];

    float* ws = (float*)d_ws;
    size_t o = 0;
    float* hist = ws + o; o += (size_t)NN*ENC;
    float* f1   = ws + o; o += (size_t)NN*ENC;
    float* f2   = ws + o; o += (size_t)NN*ENC;
    float* Af   = ws + o; o += (size_t)NN*ENC;
    float* Bfs  = ws + o; o += (size_t)NN*ENC;   // BP slot (u32 packed B-gates)
    float* As   = ws + o; o += (size_t)NN*ENC;
    float* enc  = ws + o; o += (size_t)BB*2*ENC;
    float* gi0  = ws + o; o += (size_t)BB*4*DEC;
    unsigned short* pWih  = (unsigned short*)(ws + o); o += (size_t)12*64*8/2;
    unsigned short* pWhh  = (unsigned short*)(ws + o); o += (size_t)24*64*8/2;
    unsigned short* pWdyn = (unsigned short*)(ws + o); o += (size_t)8*64*8/2;
    unsigned short* B0h = (unsigned short*)(ws + o); o += (size_t)32*4*64*8/2;
    unsigned short* B1h = (unsigned short*)(ws + o); o += (size_t)32*8*64*8/2;
    unsigned short* P1h = (unsigned short*)(ws + o); o += (size_t)2048*8/2;
    unsigned short* P1l = (unsigned short*)(ws + o); o += (size_t)2048*8/2;
    unsigned short* P2h = (unsigned short*)(ws + o); o += (size_t)2048*8/2;
    unsigned short* P2l = (unsigned short*)(ws + o); o += (size_t)2048*8/2;
    unsigned short* GIh = (unsigned short*)(ws + o); o += (size_t)8192*8/2;
    unsigned short* GIl = (unsigned short*)(ws + o); o += (size_t)8192*8/2;
    int* cnt    = (int*)(ws + o); o += NN;
    int* offv   = (int*)(ws + o); o += NN+1;
    int* curv   = (int*)(ws + o); o += NN;
    int* gtot   = (int*)(ws + o); o += 1;
    o = (o + 3) & ~(size_t)3;               // align for int2 records
    int2* recS  = (int2*)(ws + o); o += (size_t)2*EE;

    unsigned* BP = (unsigned*)Bfs;

    // h1buf (BB*OUTL*DEC = 6.4M floats) aliases Af..Bfs (2*NN*ENC = 6.4M
    // floats): both dead after cg_agg #2 (stream-ordered before lstm_mfma).
    float* h1buf = Af;

    // --- all weight prep + cnt/gtot zero in one dispatch ---
    pack_all<<<(PACK_TOTAL+255)/256, 256, 0, stream>>>(
        gWih, gWhh, Wdyn, l0Whh, l1Wih, l1Whh, l0Wih,
        c1Wf, c1Ws, c2Wf, c2Ws,
        pWih, pWhh, pWdyn, B0h, B1h, P1h, P1l, P2h, P2l, GIh, GIl, cnt, gtot);

    // --- history encoder + fused edge-count histogram ---
    encoder_mfma<<<ENCB + CNTB, 256, 0, stream>>>(
        x, Wip, bip, pWih, pWhh, gbih, gbhh, pWdyn, bdyn, hist, ei, cnt);

    // --- dst segment alloc (count done above) ---
    alloc_kernel<<<(NN+255)/256, 256, 0, stream>>>(cnt, gtot, offv, curv);

    // --- CGConv 1 (+ fused edge scatter) ---
    proj_mfma<<<PROJB + SCTB, 256, 0, stream>>>(hist, P1h, P1l, Af, As, BP,
                                                ei, ea, curv, recS);
    cg_agg<<<(NN+3)/4, 256, 0, stream>>>(hist, recS, offv, cnt,
                                         c1Wf,c1bf,c1Ws,c1bs, Af, As, BP,
                                         c1g,c1b,c1m,c1v, f1);

    // --- CGConv 2 (no scatter blocks) ---
    proj_mfma<<<PROJB, 256, 0, stream>>>(f1, P2h, P2l, Af, As, BP,
                                         ei, ea, curv, recS);
    cg_agg<<<(NN+3)/4, 256, 0, stream>>>(f1, recS, offv, cnt,
                                         c2Wf,c2bf,c2Ws,c2bs, Af, As, BP,
                                         c2g,c2b,c2m,c2v, f2);

    // --- target encoding ---
    target_kernel<<<(BB+3)/4, 256, 0, stream>>>(hist, f2, tgt, Wn, bn_, enc);

    // --- LSTM decoder prep (MFMA gi0) ---
    gi0_mfma<<<BB/16, 512, 0, stream>>>(enc, GIh, GIl, l0bih, l0bhh, gi0);

    // --- LSTM decoder (+ fused out-projection epilogue) ---
    lstm_mfma<<<BB/LMB, 512, 0, stream>>>(gi0, B0h, B1h,
                                          l1bih, l1bhh, h1buf,
                                          Wop, bop, (float*)d_out);
}

// Round 15
// 512.958 us; speedup vs baseline: 1.1917x; 1.0194x over previous
//
#include <hip/hip_runtime.h>
#include <hip/hip_fp16.h>
#include <math.h>

#define NN   50000
#define TT   16
#define EE   800000
#define BB   2000
#define EMBD 32
#define ENC  64
#define DEC  128
#define OUTL 25
#define BN_EPS 1e-5f

typedef short v8s __attribute__((ext_vector_type(8)));
typedef float v4f __attribute__((ext_vector_type(4)));
#define MFMA16(a,b,c) __builtin_amdgcn_mfma_f32_16x16x32_bf16((a),(b),(c),0,0,0)

__device__ __forceinline__ float lrelu(float v){ return v >= 0.f ? v : 0.1f*v; }
__device__ __forceinline__ float fsig(float v){ return __builtin_amdgcn_rcpf(1.f + __expf(-v)); }
__device__ __forceinline__ float ftanh(float v){ return 2.f*__builtin_amdgcn_rcpf(1.f + __expf(-2.f*v)) - 1.f; }
__device__ __forceinline__ float fsoftplus(float v){
    return v > 15.f ? v : __logf(1.f + __expf(v));
}

__device__ __forceinline__ unsigned short f2bf(float f){
    unsigned u = __float_as_uint(f);
    u = u + 0x7FFFu + ((u>>16)&1u);
    return (unsigned short)(u>>16);
}
__device__ __forceinline__ float bf2f(unsigned short s){ return __uint_as_float(((unsigned)s)<<16); }

// truncation-based hi/lo split (R12)
__device__ __forceinline__ void tsplit(float v, unsigned short& hi, unsigned short& lo){
    unsigned u = __float_as_uint(v);
    hi = (unsigned short)(u >> 16);
    float r = v - __uint_as_float(u & 0xFFFF0000u);
    lo = (unsigned short)(__float_as_uint(r) >> 16);
}

__device__ __forceinline__ v8s as_v8s(int4 v){
    union { int4 i; v8s s; } u; u.i = v; return u.s;
}

__device__ __forceinline__ void cvt8(const float* p, v8s& hi, v8s& lo){
    float4 a0 = *(const float4*)p;
    float4 a1 = *(const float4*)(p+4);
    float av[8] = {a0.x,a0.y,a0.z,a0.w,a1.x,a1.y,a1.z,a1.w};
#pragma unroll
    for (int j=0;j<8;j++){
        unsigned short h = f2bf(av[j]);
        hi[j] = (short)h;
        lo[j] = (short)f2bf(av[j] - bf2f(h));
    }
}
// reconstruct hi+lo, lrelu, re-split
__device__ __forceinline__ void lrelu_resplit(v8s hh, v8s hl, v8s& oh, v8s& ol){
#pragma unroll
    for (int j=0;j<8;j++){
        float v = bf2f((unsigned short)hh[j]) + bf2f((unsigned short)hl[j]);
        float a = lrelu(v);
        unsigned short h = f2bf(a);
        oh[j] = (short)h;
        ol[j] = (short)f2bf(a - bf2f(h));
    }
}

// ---------------- fused packing helpers ----------------
__device__ __forceinline__ void pf_item(const float* W, int K, int KB, int i,
                                        unsigned short* out){
    int l = i & 63, fb = i >> 6;
    int kb = fb % KB, nt = fb / KB;
    int n = nt*16 + (l&15);
    int k0 = kb*32 + ((l>>4)*8);
#pragma unroll
    for (int j=0;j<8;j++) out[i*8+j] = f2bf(W[(size_t)n*K + k0 + j]);
}
__device__ __forceinline__ void phl_item(const float* W, int K, int KB, int i,
                                         unsigned short* hi, unsigned short* lo){
    int l = i & 63, fb = i >> 6;
    int kb = fb % KB, nt = fb / KB;
    int n = nt*16 + (l&15);
    int k0 = kb*32 + ((l>>4)*8);
#pragma unroll
    for (int j=0;j<8;j++){
        float v = W[(size_t)n*K + k0 + j];
        unsigned short h = f2bf(v);
        hi[i*8+j] = h;
        lo[i*8+j] = f2bf(v - bf2f(h));
    }
}
__device__ __forceinline__ void pcat_item(const float* Wa, const float* Wb,
                                          int K1, int K, int KB, int i,
                                          unsigned short* out){
    int l = i & 63, fb = i >> 6;
    int kb = fb % KB, nt = fb / KB;
    int n = nt*16 + (l&15);
    int k0 = kb*32 + ((l>>4)*8);
#pragma unroll
    for (int j=0;j<8;j++){
        int k = k0 + j;
        float v = (k < K1) ? Wa[(size_t)n*K1 + k] : Wb[(size_t)n*(K-K1) + (k-K1)];
        out[i*8+j] = f2bf(v);
    }
}
__device__ __forceinline__ void pproj_item(const float* Wf, const float* Ws, int i,
                                           unsigned short* hi, unsigned short* lo){
    int l = i & 63, fb = i >> 6;
    int kb = fb & 1, nt = fb >> 1;
    int n = nt*16 + (l&15);
    int d = n >> 6, c = n & 63;
    const float* W = (d < 2) ? Wf : Ws;
    int k0 = (d&1)*64 + kb*32 + ((l>>4)*8);
#pragma unroll
    for (int j=0;j<8;j++){
        float v = W[c*130 + k0 + j];
        unsigned short h = f2bf(v);
        hi[i*8+j] = h;
        lo[i*8+j] = f2bf(v - bf2f(h));
    }
}

// ---------------- all weight prep in ONE dispatch ----------------
__global__ void pack_all(
    const float* __restrict__ gWih, const float* __restrict__ gWhh,
    const float* __restrict__ Wdyn,
    const float* __restrict__ l0Whh, const float* __restrict__ l1Wih,
    const float* __restrict__ l1Whh, const float* __restrict__ l0Wih,
    const float* __restrict__ c1Wf, const float* __restrict__ c1Ws,
    const float* __restrict__ c2Wf, const float* __restrict__ c2Ws,
    unsigned short* __restrict__ pWih, unsigned short* __restrict__ pWhh,
    unsigned short* __restrict__ pWdyn,
    unsigned short* __restrict__ B0h, unsigned short* __restrict__ B1h,
    unsigned short* __restrict__ P1h, unsigned short* __restrict__ P1l,
    unsigned short* __restrict__ P2h, unsigned short* __restrict__ P2l,
    unsigned short* __restrict__ GIh, unsigned short* __restrict__ GIl,
    int* __restrict__ cnt, int* __restrict__ gtot)
{
    int i = blockIdx.x*256 + threadIdx.x;
    if (i < 768){ pf_item(gWih, 32, 1, i, pWih); return; }   i -= 768;
    if (i < 1536){ pf_item(gWhh, 64, 2, i, pWhh); return; }  i -= 1536;
    if (i < 512){ pf_item(Wdyn, 64, 2, i, pWdyn); return; }  i -= 512;
    if (i < 8192){ pcat_item(l0Whh, l0Whh, 128, 128, 4, i, B0h); return; } i -= 8192;
    if (i < 16384){ pcat_item(l1Wih, l1Whh, 128, 256, 8, i, B1h); return; } i -= 16384;
    if (i < 2048){ pproj_item(c1Wf, c1Ws, i, P1h, P1l); return; } i -= 2048;
    if (i < 2048){ pproj_item(c2Wf, c2Ws, i, P2h, P2l); return; } i -= 2048;
    if (i < 8192){ phl_item(l0Wih, 128, 4, i, GIh, GIl); return; } i -= 8192;
    if (i < NN){ cnt[i] = 0; return; } i -= NN;
    if (i < 1){ gtot[0] = 0; return; }
}
#define PACK_TOTAL (768+1536+512+8192+16384+2048+2048+8192+NN+1)

// ---------------- GRU encoder v13: + fused edge-count histogram (unchanged) ----------------
#define ENCB (NN/16)
#define CNTB ((EE+255)/256)
__global__ __launch_bounds__(256) void encoder_mfma(
    const float* __restrict__ x,
    const float* __restrict__ Wip, const float* __restrict__ bip,
    const unsigned short* __restrict__ pWih,
    const unsigned short* __restrict__ pWhh,
    const float* __restrict__ bih, const float* __restrict__ bhh,
    const unsigned short* __restrict__ pWdyn,
    const float* __restrict__ bdyn,
    float* __restrict__ hist,
    const int* __restrict__ ei, int* __restrict__ cnt)
{
    __shared__ unsigned short efh[4*512], efl[4*512];          // e A-frags, 4-step window
    __shared__ unsigned short hfh[2][1024], hfl[2][1024];      // dbuf h A-frags (swizzled)
    const int tid = threadIdx.x;

    if (blockIdx.x >= ENCB){
        int e = (blockIdx.x - ENCB)*256 + tid;
        if (e < EE) atomicAdd(&cnt[ei[EE+e]], 1);
        return;
    }

    const int l   = tid & 63;
    const int w   = tid >> 6;          // wave owns g-tile w
    const int ln  = l & 15, q = l >> 4;
    const int blk = blockIdx.x;
    const int rsw = ((l>>1)&7)<<3;     // read swizzle key

    for (int i = tid; i < 1024; i += 256){
        hfh[0][i]=0; hfl[0][i]=0; hfh[1][i]=0; hfl[1][i]=0;
    }

    // e-compute decomposition: thread owns ONE k (3 weight regs) + 2 nodes
    const int k0 = tid & 31;
    const int mb = tid >> 5;           // nodes 2mb, 2mb+1
    const float ew0 = Wip[2*k0], ew1 = Wip[2*k0+1], ebk = bip[k0];
    const int ebase = (k0>>3)*128 + (k0&7);
    const float2* xr0 = (const float2*)(x + (size_t)(blk*16 + 2*mb    )*32);
    const float2* xr1 = (const float2*)(x + (size_t)(blk*16 + 2*mb + 1)*32);

    const int c = w*16 + ln;
    const float bR  = bih[c]       + bhh[c];
    const float bZ  = bih[64 + c]  + bhh[64 + c];
    const float bNI = bih[128 + c];
    const float bNH = bhh[128 + c];
    float hprev[4] = {0.f,0.f,0.f,0.f};

    const v8s* FIH = (const v8s*)pWih;
    const v8s* FHH = (const v8s*)pWhh;
    const v8s* FDY = (const v8s*)pWdyn;
    const int wbase = (c>>5)*512 + (16*((c&31)>>3))*8 + (c&7);
    __syncthreads();                   // h zero-init ready

    int p = 0;
#pragma unroll 1
    for (int tb = 0; tb < 4; tb++){
#pragma unroll
        for (int ts = 0; ts < 4; ts++){
            int t = tb*4 + ts;
            float2 xv0 = xr0[t], xv1 = xr1[t];
            float e0 = lrelu(ew0*xv0.x + ew1*xv0.y + ebk);
            float e1 = lrelu(ew0*xv1.x + ew1*xv1.y + ebk);
            unsigned short h_, l_;
            tsplit(e0, h_, l_);
            efh[ts*512 + ebase + (2*mb  )*8] = h_;
            efl[ts*512 + ebase + (2*mb  )*8] = l_;
            tsplit(e1, h_, l_);
            efh[ts*512 + ebase + (2*mb+1)*8] = h_;
            efl[ts*512 + ebase + (2*mb+1)*8] = l_;
        }
        __syncthreads();               // ef window ready
#pragma unroll 1
        for (int ts = 0; ts < 4; ts++){
            v8s eh  = *(const v8s*)&efh[ts*512 + l*8];
            v8s el  = *(const v8s*)&efl[ts*512 + l*8];
            v8s h0h = *(const v8s*)&hfh[p][(l*8) ^ rsw];
            v8s h0l = *(const v8s*)&hfl[p][(l*8) ^ rsw];
            v8s h1h = *(const v8s*)&hfh[p][512 + ((l*8) ^ rsw)];
            v8s h1l = *(const v8s*)&hfl[p][512 + ((l*8) ^ rsw)];

            v4f aR = {bR,bR,bR,bR};
            v4f aZ = {bZ,bZ,bZ,bZ};
            v4f aNI= {bNI,bNI,bNI,bNI};
            v4f aNH= {bNH,bNH,bNH,bNH};
            v8s b;
            b = FIH[(w   )*64 + l];    aR = MFMA16(eh,b,aR);  aR = MFMA16(el,b,aR);
            b = FHH[(w*2+0)*64+l];     aR = MFMA16(h0h,b,aR); aR = MFMA16(h0l,b,aR);
            b = FHH[(w*2+1)*64+l];     aR = MFMA16(h1h,b,aR); aR = MFMA16(h1l,b,aR);
            b = FIH[(4+w )*64 + l];    aZ = MFMA16(eh,b,aZ);  aZ = MFMA16(el,b,aZ);
            b = FHH[((4+w)*2+0)*64+l]; aZ = MFMA16(h0h,b,aZ); aZ = MFMA16(h0l,b,aZ);
            b = FHH[((4+w)*2+1)*64+l]; aZ = MFMA16(h1h,b,aZ); aZ = MFMA16(h1l,b,aZ);
            b = FIH[(8+w )*64 + l];    aNI= MFMA16(eh,b,aNI); aNI= MFMA16(el,b,aNI);
            b = FHH[((8+w)*2+0)*64+l]; aNH= MFMA16(h0h,b,aNH);aNH= MFMA16(h0l,b,aNH);
            b = FHH[((8+w)*2+1)*64+l]; aNH= MFMA16(h1h,b,aNH);aNH= MFMA16(h1l,b,aNH);

#pragma unroll
            for (int i = 0; i < 4; i++){
                float r_ = fsig(aR[i]);
                float z_ = fsig(aZ[i]);
                float nn_ = ftanh(aNI[i] + r_*aNH[i]);
                float hn = nn_ + z_*(hprev[i] - nn_);
                hprev[i] = hn;
                int row = q*4 + i;
                int off = (wbase + row*8) ^ ((((row)>>1)&7)<<3);
                unsigned short hh_, hl_;
                tsplit(hn, hh_, hl_);
                hfh[1-p][off] = hh_;
                hfl[1-p][off] = hl_;
            }
            __syncthreads();   // per-step barrier
            p ^= 1;
        }
    }
    {
        v8s a0h,a0l,a1h,a1l;
        lrelu_resplit(*(const v8s*)&hfh[p][(l*8) ^ rsw],
                      *(const v8s*)&hfl[p][(l*8) ^ rsw],       a0h, a0l);
        lrelu_resplit(*(const v8s*)&hfh[p][512 + ((l*8) ^ rsw)],
                      *(const v8s*)&hfl[p][512 + ((l*8) ^ rsw)], a1h, a1l);
        const int nt = w;
        float bb = bdyn[nt*16 + ln];
        v4f acc = {bb,bb,bb,bb};
        v8s b;
        b = FDY[(nt*2+0)*64 + l]; acc = MFMA16(a0h,b,acc); acc = MFMA16(a0l,b,acc);
        b = FDY[(nt*2+1)*64 + l]; acc = MFMA16(a1h,b,acc); acc = MFMA16(a1l,b,acc);
#pragma unroll
        for (int i = 0; i < 4; i++){
            hist[(size_t)(blk*16 + q*4 + i)*64 + nt*16 + ln] = lrelu(acc[i]);
        }
    }
}

// ---------------- CGConv projections v3: + fused scatter (unchanged) ----------------
#define PROJB ((NN+63)/64)
#define SCTB  ((EE+255)/256)
#define PROJ_ACC(NT, ACC) { \
    v8s bh0_ = FH[((NT)*2+0)*64 + l], bl0_ = FL[((NT)*2+0)*64 + l]; \
    v8s bh1_ = FH[((NT)*2+1)*64 + l], bl1_ = FL[((NT)*2+1)*64 + l]; \
    ACC = MFMA16(ah0,bh0_,ACC); ACC = MFMA16(al0,bh0_,ACC); ACC = MFMA16(ah0,bl0_,ACC); \
    ACC = MFMA16(ah1,bh1_,ACC); ACC = MFMA16(al1,bh1_,ACC); ACC = MFMA16(ah1,bl1_,ACC); }

__global__ __launch_bounds__(256) void proj_mfma(
    const float* __restrict__ xin,
    const unsigned short* __restrict__ Bh, const unsigned short* __restrict__ Bl,
    float* __restrict__ Af, float* __restrict__ As,
    unsigned* __restrict__ BP,
    const int* __restrict__ ei, const float* __restrict__ ea,
    int* __restrict__ cur, int2* __restrict__ recS)
{
    __shared__ float sx[64*68];
    const int tid = threadIdx.x;

    if (blockIdx.x >= PROJB){
        int e = (blockIdx.x - PROJB)*256 + tid;
        if (e < EE){
            int d = ei[EE+e];
            int p = atomicAdd(&cur[d], 1);
            unsigned e0 = __half_as_ushort(__float2half(ea[2*(size_t)e]));
            unsigned e1 = __half_as_ushort(__float2half(ea[2*(size_t)e+1]));
            int2 r;
            r.x = ei[e];
            r.y = (int)(e0 | (e1 << 16));
            recS[p] = r;
        }
        return;
    }

    const int l = tid & 63;
    const int w = tid >> 6;
    const int ln = l & 15, q = l >> 4;
    const int n0 = blockIdx.x*64;

    for (int i=tid;i<64*16;i+=256){
        int nn = i>>4, f4 = i&15;
        float4 v = {0.f,0.f,0.f,0.f};
        if (n0+nn < NN) v = ((const float4*)(xin + (size_t)(n0+nn)*64))[f4];
        *(float4*)&sx[nn*68 + f4*4] = v;
    }
    __syncthreads();

    v8s ah0,al0,ah1,al1;
    cvt8(&sx[(w*16+ln)*68 +      q*8], ah0, al0);
    cvt8(&sx[(w*16+ln)*68 + 32 + q*8], ah1, al1);

    const v8s* FH = (const v8s*)Bh;
    const v8s* FL = (const v8s*)Bl;
#pragma unroll 1
    for (int c3=0; c3<4; c3++){
        v4f aA = {0.f,0.f,0.f,0.f};
        v4f aS = aA, aF = aA, aB = aA;
        PROJ_ACC(c3,      aA);
        PROJ_ACC(8 + c3,  aS);
        PROJ_ACC(4 + c3,  aF);
        PROJ_ACC(12 + c3, aB);
        int col = c3*16 + ln;
#pragma unroll
        for (int i=0;i<4;i++){
            int node = n0 + w*16 + q*4 + i;
            if (node < NN){
                Af[(size_t)node*64 + col] = aA[i];
                As[(size_t)node*64 + col] = aS[i];
                unsigned pf = __half_as_ushort(__float2half(aF[i]));
                unsigned ps = __half_as_ushort(__float2half(aB[i]));
                BP[(size_t)node*64 + col] = pf | (ps << 16);
            }
        }
    }
}

// ---------------- dst segment build: alloc ----------------
__global__ void alloc_kernel(const int* __restrict__ cnt, int* __restrict__ gtot,
                             int* __restrict__ off, int* __restrict__ cur){
    int n = blockIdx.x*256 + threadIdx.x;
    if (n >= NN) return;
    int c = cnt[n];
    int s = atomicAdd(gtot, c);
    off[n] = s;
    cur[n] = s;
}

// ---------------- CGConv aggregate: 8-edge unroll (R15) ----------------
__device__ __forceinline__ float edge_term(
    int2 r, const unsigned* BPc,
    float afd, float asd, float wf0, float wf1, float ws0, float ws1)
{
    unsigned ea = (unsigned)r.y;
    float e0 = __half2float(__ushort_as_half((unsigned short)(ea & 0xFFFFu)));
    float e1 = __half2float(__ushort_as_half((unsigned short)(ea >> 16)));
    unsigned pv = BPc[(size_t)r.x*64];
    float bfv = __half2float(__ushort_as_half((unsigned short)(pv & 0xFFFFu)));
    float bsv = __half2float(__ushort_as_half((unsigned short)(pv >> 16)));
    float gf = afd + bfv + wf0*e0 + wf1*e1;
    float gs = asd + bsv + ws0*e0 + ws1*e1;
    return fsig(gf)*fsoftplus(gs);
}

__global__ __launch_bounds__(256) void cg_agg(
    const float* __restrict__ xin,
    const int2* __restrict__ recS,
    const int* __restrict__ off, const int* __restrict__ cnt,
    const float* __restrict__ Wf, const float* __restrict__ bf,
    const float* __restrict__ Ws, const float* __restrict__ bs,
    const float* __restrict__ Af, const float* __restrict__ As,
    const unsigned* __restrict__ BP,
    const float* __restrict__ gamma, const float* __restrict__ beta,
    const float* __restrict__ mean, const float* __restrict__ var,
    float* __restrict__ outp)
{
    const int tid = threadIdx.x;
    const int c = tid & 63, wid = tid >> 6;
    const int n = blockIdx.x*4 + wid;
    if (n >= NN) return;

    const float wf0 = Wf[c*130+128], wf1 = Wf[c*130+129], bfc = bf[c];
    const float ws0 = Ws[c*130+128], ws1 = Ws[c*130+129], bsc = bs[c];
    const float afd = Af[(size_t)n*64+c] + bfc, asd = As[(size_t)n*64+c] + bsc;
    const unsigned* BPc = BP + c;

    float acc = 0.f;
    int i = off[n];
    const int i1 = i + cnt[n];
#pragma unroll 1
    for (; i+7 < i1; i += 8){
        int2 r0 = recS[i],   r1 = recS[i+1], r2 = recS[i+2], r3 = recS[i+3];
        int2 r4 = recS[i+4], r5 = recS[i+5], r6 = recS[i+6], r7 = recS[i+7];
        acc += edge_term(r0, BPc, afd, asd, wf0, wf1, ws0, ws1);
        acc += edge_term(r1, BPc, afd, asd, wf0, wf1, ws0, ws1);
        acc += edge_term(r2, BPc, afd, asd, wf0, wf1, ws0, ws1);
        acc += edge_term(r3, BPc, afd, asd, wf0, wf1, ws0, ws1);
        acc += edge_term(r4, BPc, afd, asd, wf0, wf1, ws0, ws1);
        acc += edge_term(r5, BPc, afd, asd, wf0, wf1, ws0, ws1);
        acc += edge_term(r6, BPc, afd, asd, wf0, wf1, ws0, ws1);
        acc += edge_term(r7, BPc, afd, asd, wf0, wf1, ws0, ws1);
    }
#pragma unroll 1
    for (; i+3 < i1; i += 4){
        int2 r0 = recS[i], r1 = recS[i+1], r2 = recS[i+2], r3 = recS[i+3];
        acc += edge_term(r0, BPc, afd, asd, wf0, wf1, ws0, ws1);
        acc += edge_term(r1, BPc, afd, asd, wf0, wf1, ws0, ws1);
        acc += edge_term(r2, BPc, afd, asd, wf0, wf1, ws0, ws1);
        acc += edge_term(r3, BPc, afd, asd, wf0, wf1, ws0, ws1);
    }
#pragma unroll 1
    for (; i < i1; i++){
        acc += edge_term(recS[i], BPc, afd, asd, wf0, wf1, ws0, ws1);
    }
    float bn = (acc - mean[c])*rsqrtf(var[c]+BN_EPS)*gamma[c] + beta[c];
    outp[(size_t)n*64+c] = xin[(size_t)n*64+c] + bn;
}

// ---------------- target gather + nbrs linear + concat (unchanged) ----------------
__global__ __launch_bounds__(256) void target_kernel(
    const float* __restrict__ hist, const float* __restrict__ f2,
    const int* __restrict__ tgt,
    const float* __restrict__ Wn, const float* __restrict__ bn_,
    float* __restrict__ enc)
{
    const int tid=threadIdx.x;
    const int c = tid&63, q = tid>>6;
    const int b = blockIdx.x*4 + q;
    if (b>=BB) return;
    const int n = tgt[b];
    float a = bn_[c];
#pragma unroll
    for (int k=0;k<ENC;k++) a += Wn[c*64+k]*f2[(size_t)n*64+k];
    enc[(size_t)b*128 + 64 + c] = lrelu(a);
    enc[(size_t)b*128 + c]      = hist[(size_t)n*64+c];
}

// ---------------- 2-layer LSTM decoder + fused gi0 prologue + out-proj epilogue ----------------
// R15: gi0_mfma had the SAME block shape (512 thr / 16 batch rows) as lstm.
// Fused into the prologue: stage enc (16x132 f32) into the sW0 LDS region,
// run the identical cvt8+MFMA, exchange the layout mismatch through a 32KB
// LDS gi0 buffer (still inside sW0's 128KB, before sW0 is staged), read rgi,
// barrier, then stage sW0 over it. Deletes the gi0 dispatch + 8MB HBM
// round-trip. Bit-identical math. Prologue registers are transient (die
// before the t-loop) — no R11-style loop spill risk.
#define LMB 16
__global__ __launch_bounds__(512)
__attribute__((amdgpu_waves_per_eu(2,2)))
void lstm_mfma(
    const float* __restrict__ enc,
    const unsigned short* __restrict__ GIh, const unsigned short* __restrict__ GIl,
    const float* __restrict__ bih0, const float* __restrict__ bhh0,
    const unsigned short* __restrict__ B0h,
    const unsigned short* __restrict__ B1h,
    const float* __restrict__ bih1, const float* __restrict__ bhh1,
    float* __restrict__ h1buf,
    const float* __restrict__ Wop, const float* __restrict__ bop,
    float* __restrict__ outp)
{
    __shared__ int4 sW0[32*4*64];                                // 131072 B
    __shared__ unsigned short h0hi[2][4*512], h0lo[2][4*512];    // 16384 B
    __shared__ unsigned short h1hi[2][4*512], h1lo[2][4*512];    // 16384 B
    const int tid = threadIdx.x;
    const int l = tid & 63;
    const int w = tid >> 6;
    const int c = l & 15;
    const int q = l >> 4;
    const int j = w*16 + c;
    const int b0 = blockIdx.x*LMB;
    const int lsw = ((l>>1)&7)<<3;     // read swizzle key (row = l)

    // ---- fused gi0 prologue (uses sW0's LDS space before sW0 is staged) ----
    float rgi[4][4];
    {
        float* sEnc = (float*)sW0;                 // 16*132 f32 = 8448 B
        float* sGi  = (float*)sW0 + 16*132;        // 16*512 f32 = 32768 B
        for (int i=tid;i<16*32;i+=512){
            int row = i>>5, f4 = i&31;
            *(float4*)&sEnc[row*132 + f4*4] = ((const float4*)(enc + (size_t)(b0+row)*128))[f4];
        }
        __syncthreads();

        v8s ah[4], al[4];
#pragma unroll
        for (int kb=0;kb<4;kb++) cvt8(&sEnc[c*132 + kb*32 + q*8], ah[kb], al[kb]);

        const v8s* FH = (const v8s*)GIh;
        const v8s* FL = (const v8s*)GIl;
#pragma unroll
        for (int u=0;u<4;u++){
            int nt = w*4 + u;
            int col = nt*16 + c;
            float bb = bih0[col] + bhh0[col];
            v4f acc = {bb,bb,bb,bb};
#pragma unroll
            for (int kb=0;kb<4;kb++){
                v8s bh = FH[(nt*4+kb)*64 + l];
                v8s bl = FL[(nt*4+kb)*64 + l];
                acc = MFMA16(ah[kb],bh,acc); acc = MFMA16(al[kb],bh,acc); acc = MFMA16(ah[kb],bl,acc);
            }
#pragma unroll
            for (int i=0;i<4;i++)
                sGi[(q*4 + i)*512 + col] = acc[i];
        }
        __syncthreads();               // gi0 exchange ready
#pragma unroll
        for (int g=0;g<4;g++)
#pragma unroll
            for (int i=0;i<4;i++)
                rgi[g][i] = sGi[(q*4 + i)*512 + g*128 + j];
        __syncthreads();               // reads done; sW0 staging may overwrite
    }

    {
        const int4* F0 = (const int4*)B0h;
        for (int i=tid;i<32*4*64;i+=512) sW0[i] = F0[i];
    }
    for (int i=tid;i<4*512;i+=512){
        h0hi[0][i]=0; h0lo[0][i]=0; h0hi[1][i]=0; h0lo[1][i]=0;
        h1hi[0][i]=0; h1lo[0][i]=0; h1hi[1][i]=0; h1lo[1][i]=0;
    }

    int4 W1r[32];
    {
        const int4* F1 = (const int4*)B1h;
#pragma unroll
        for (int g=0;g<4;g++)
#pragma unroll
            for (int kb=0;kb<8;kb++) W1r[g*8+kb] = F1[((g*8+w)*8 + kb)*64 + l];
#pragma unroll
        for (int i=0;i<32;i++)
            asm volatile("" : "+v"(W1r[i].x), "+v"(W1r[i].y), "+v"(W1r[i].z), "+v"(W1r[i].w));
    }

    float b1[4];
#pragma unroll
    for (int g=0;g<4;g++) b1[g] = bih1[g*128+j] + bhh1[g*128+j];
    float c0[4] = {0,0,0,0}, c1[4] = {0,0,0,0};
    const int kbw = j>>5, qw = (j>>3)&3, jw = j&7;
    __syncthreads();

    int p = 0;
#pragma unroll 1
    for (int t=0;t<OUTL;t++){
        // ---- layer 0: read h0[p], write h0[1-p]; dual hi/lo accumulators ----
        v4f aH[4], aL[4];
#pragma unroll
        for (int g=0;g<4;g++){
            v4f t4 = {rgi[g][0], rgi[g][1], rgi[g][2], rgi[g][3]};
            aH[g] = t4;
            v4f z = {0.f,0.f,0.f,0.f};
            aL[g] = z;
        }
#pragma unroll
        for (int kb=0;kb<4;kb++){
            v8s ah = *(const v8s*)&h0hi[p][kb*512 + ((l*8) ^ lsw)];
            v8s al = *(const v8s*)&h0lo[p][kb*512 + ((l*8) ^ lsw)];
#pragma unroll
            for (int g=0;g<4;g++){
                v8s bfr = as_v8s(sW0[((g*8+w)*4 + kb)*64 + l]);
                aH[g] = MFMA16(ah, bfr, aH[g]);
                aL[g] = MFMA16(al, bfr, aL[g]);
            }
        }
#pragma unroll
        for (int i=0;i<4;i++){
            float gi_ = aH[0][i]+aL[0][i], gf_ = aH[1][i]+aL[1][i];
            float gg_ = aH[2][i]+aL[2][i], go_ = aH[3][i]+aL[3][i];
            c0[i] = fsig(gf_)*c0[i] + fsig(gi_)*ftanh(gg_);
            float hn = fsig(go_)*ftanh(c0[i]);
            int row = q*4 + i;
            int off = (kbw*512 + (qw*16 + row)*8 + jw) ^ (((row>>1)&7)<<3);
            unsigned short h = f2bf(hn);
            h0hi[1-p][off] = h;
            h0lo[1-p][off] = f2bf(hn - bf2f(h));
        }
        __syncthreads();   // B1: the ONLY barrier per step

        // ---- layer 1: read h0[1-p] + h1[p], write h1[1-p] ----
        v4f bH[4], bL[4];
#pragma unroll
        for (int g=0;g<4;g++){
            v4f t4={b1[g],b1[g],b1[g],b1[g]}; bH[g]=t4;
            v4f z={0.f,0.f,0.f,0.f}; bL[g]=z;
        }
#pragma unroll
        for (int kb=0;kb<8;kb++){
            const unsigned short* hb = (kb<4) ? h0hi[1-p] : h1hi[p];
            const unsigned short* lb = (kb<4) ? h0lo[1-p] : h1lo[p];
            int kk = kb & 3;
            v8s ah = *(const v8s*)&hb[kk*512 + ((l*8) ^ lsw)];
            v8s al = *(const v8s*)&lb[kk*512 + ((l*8) ^ lsw)];
#pragma unroll
            for (int g=0;g<4;g++){
                bH[g] = MFMA16(ah, as_v8s(W1r[g*8+kb]), bH[g]);
                bL[g] = MFMA16(al, as_v8s(W1r[g*8+kb]), bL[g]);
            }
        }
        float h1new[4];
#pragma unroll
        for (int i=0;i<4;i++){
            float gi_ = bH[0][i]+bL[0][i], gf_ = bH[1][i]+bL[1][i];
            float gg_ = bH[2][i]+bL[2][i], go_ = bH[3][i]+bL[3][i];
            c1[i] = fsig(gf_)*c1[i] + fsig(gi_)*ftanh(gg_);
            h1new[i] = fsig(go_)*ftanh(c1[i]);
            int row = q*4 + i;
            int off = (kbw*512 + (qw*16 + row)*8 + jw) ^ (((row>>1)&7)<<3);
            unsigned short h = f2bf(h1new[i]);
            h1hi[1-p][off] = h;
            h1lo[1-p][off] = f2bf(h1new[i] - bf2f(h));
        }

        // ---- out-proj deferred: stream h1 (f32) to global scratch ----
#pragma unroll
        for (int i=0;i<4;i++){
            h1buf[((size_t)(b0 + q*4 + i)*OUTL + t)*DEC + j] = h1new[i];
        }
        p ^= 1;
    }

    // ---- fused out-projection epilogue: this block's 16x25 rows ----
    __syncthreads();    // block-scope fence: h1buf writes visible
    {
        const float bo0 = bop[0], bo1 = bop[1];
        const float4* w0 = (const float4*)Wop;
        const float4* w1 = (const float4*)(Wop + DEC);
        for (int r = tid; r < LMB*OUTL; r += 512){
            int b = b0 + r/OUTL, t = r%OUTL;
            const float4* hp = (const float4*)(h1buf + ((size_t)b*OUTL + t)*DEC);
            float a0 = 0.f, a1 = 0.f;
#pragma unroll
            for (int k=0;k<32;k++){
                float4 h = hp[k], x0 = w0[k], x1 = w1[k];
                a0 += h.x*x0.x + h.y*x0.y + h.z*x0.z + h.w*x0.w;
                a1 += h.x*x1.x + h.y*x1.y + h.z*x1.z + h.w*x1.w;
            }
            outp[((size_t)b*OUTL + t)*2    ] = a0 + bo0;
            outp[((size_t)b*OUTL + t)*2 + 1] = a1 + bo1;
        }
    }
}

extern "C" void kernel_launch(void* const* d_in, const int* in_sizes, int n_in,
                              void* d_out, int out_size, void* d_ws, size_t ws_size,
                              hipStream_t stream)
{
    const float* x    = (const float*)d_in[0];
    const int*   ei   = (const int*)d_in[1];
    const float* ea   = (const float*)d_in[2];
    const int*   tgt  = (const int*)d_in[3];
    const float* Wip  = (const float*)d_in[4];
    const float* bip  = (const float*)d_in[5];
    const float* gWih = (const float*)d_in[6];
    const float* gWhh = (const float*)d_in[7];
    const float* gbih = (const float*)d_in[8];
    const float* gbhh = (const float*)d_in[9];
    const float* Wdyn = (const float*)d_in[10];
    const float* bdyn = (const float*)d_in[11];
    const float* c1Wf=(const float*)d_in[12]; const float* c1bf=(const float*)d_in[13];
    const float* c1Ws=(const float*)d_in[14]; const float* c1bs=(const float*)d_in[15];
    const float* c1g =(const float*)d_in[16]; const float* c1b =(const float*)d_in[17];
    const float* c1m =(const float*)d_in[18]; const float* c1v =(const float*)d_in[19];
    const float* c2Wf=(const float*)d_in[20]; const float* c2bf=(const float*)d_in[21];
    const float* c2Ws=(const float*)d_in[22]; const float* c2bs=(const float*)d_in[23];
    const float* c2g =(const float*)d_in[24]; const float* c2b =(const float*)d_in[25];
    const float* c2m =(const float*)d_in[26]; const float* c2v =(const float*)d_in[27];
    const float* Wn  =(const float*)d_in[28]; const float* bn_ =(const float*)d_in[29];
    const float* l0Wih=(const float*)d_in[30]; const float* l0Whh=(const float*)d_in[31];
    const float* l0bih=(const float*)d_in[32]; const float* l0bhh=(const float*)d_in[33];
    const float* l1Wih=(const float*)d_in[34]; const float* l1Whh=(const float*)d_in[35];
    const float* l1bih=(const float*)d_in[36]; const float* l1bhh=(const float*)d_in[37];
    const float* Wop =(const float*)d_in[38]; const float* bop=(const float*)d_in[39];

    float* ws = (float*)d_ws;
    size_t o = 0;
    float* hist = ws + o; o += (size_t)NN*ENC;
    float* f1   = ws + o; o += (size_t)NN*ENC;
    float* f2   = ws + o; o += (size_t)NN*ENC;
    float* Af   = ws + o; o += (size_t)NN*ENC;
    float* Bfs  = ws + o; o += (size_t)NN*ENC;   // BP slot (u32 packed B-gates)
    float* As   = ws + o; o += (size_t)NN*ENC;
    float* enc  = ws + o; o += (size_t)BB*2*ENC;
    unsigned short* pWih  = (unsigned short*)(ws + o); o += (size_t)12*64*8/2;
    unsigned short* pWhh  = (unsigned short*)(ws + o); o += (size_t)24*64*8/2;
    unsigned short* pWdyn = (unsigned short*)(ws + o); o += (size_t)8*64*8/2;
    unsigned short* B0h = (unsigned short*)(ws + o); o += (size_t)32*4*64*8/2;
    unsigned short* B1h = (unsigned short*)(ws + o); o += (size_t)32*8*64*8/2;
    unsigned short* P1h = (unsigned short*)(ws + o); o += (size_t)2048*8/2;
    unsigned short* P1l = (unsigned short*)(ws + o); o += (size_t)2048*8/2;
    unsigned short* P2h = (unsigned short*)(ws + o); o += (size_t)2048*8/2;
    unsigned short* P2l = (unsigned short*)(ws + o); o += (size_t)2048*8/2;
    unsigned short* GIh = (unsigned short*)(ws + o); o += (size_t)8192*8/2;
    unsigned short* GIl = (unsigned short*)(ws + o); o += (size_t)8192*8/2;
    int* cnt    = (int*)(ws + o); o += NN;
    int* offv   = (int*)(ws + o); o += NN+1;
    int* curv   = (int*)(ws + o); o += NN;
    int* gtot   = (int*)(ws + o); o += 1;
    o = (o + 3) & ~(size_t)3;               // align for int2 records
    int2* recS  = (int2*)(ws + o); o += (size_t)2*EE;

    unsigned* BP = (unsigned*)Bfs;

    // h1buf (BB*OUTL*DEC = 6.4M floats) aliases Af..Bfs (2*NN*ENC = 6.4M
    // floats): both dead after cg_agg #2 (stream-ordered before lstm_mfma).
    float* h1buf = Af;

    // --- all weight prep + cnt/gtot zero in one dispatch ---
    pack_all<<<(PACK_TOTAL+255)/256, 256, 0, stream>>>(
        gWih, gWhh, Wdyn, l0Whh, l1Wih, l1Whh, l0Wih,
        c1Wf, c1Ws, c2Wf, c2Ws,
        pWih, pWhh, pWdyn, B0h, B1h, P1h, P1l, P2h, P2l, GIh, GIl, cnt, gtot);

    // --- history encoder + fused edge-count histogram ---
    encoder_mfma<<<ENCB + CNTB, 256, 0, stream>>>(
        x, Wip, bip, pWih, pWhh, gbih, gbhh, pWdyn, bdyn, hist, ei, cnt);

    // --- dst segment alloc (count done above) ---
    alloc_kernel<<<(NN+255)/256, 256, 0, stream>>>(cnt, gtot, offv, curv);

    // --- CGConv 1 (+ fused edge scatter) ---
    proj_mfma<<<PROJB + SCTB, 256, 0, stream>>>(hist, P1h, P1l, Af, As, BP,
                                                ei, ea, curv, recS);
    cg_agg<<<(NN+3)/4, 256, 0, stream>>>(hist, recS, offv, cnt,
                                         c1Wf,c1bf,c1Ws,c1bs, Af, As, BP,
                                         c1g,c1b,c1m,c1v, f1);

    // --- CGConv 2 (no scatter blocks) ---
    proj_mfma<<<PROJB, 256, 0, stream>>>(f1, P2h, P2l, Af, As, BP,
                                         ei, ea, curv, recS);
    cg_agg<<<(NN+3)/4, 256, 0, stream>>>(f1, recS, offv, cnt,
                                         c2Wf,c2bf,c2Ws,c2bs, Af, As, BP,
                                         c2g,c2b,c2m,c2v, f2);

    // --- target encoding ---
    target_kernel<<<(BB+3)/4, 256, 0, stream>>>(hist, f2, tgt, Wn, bn_, enc);

    // --- LSTM decoder (fused gi0 prologue + out-projection epilogue) ---
    lstm_mfma<<<BB/LMB, 512, 0, stream>>>(enc, GIh, GIl, l0bih, l0bhh,
                                          B0h, B1h, l1bih, l1bhh, h1buf,
                                          Wop, bop, (float*)d_out);
}